// Round 1
// baseline (12248.243 us; speedup 1.0000x reference)
//
#include <hip/hip_runtime.h>
#include <hip/hip_bf16.h>
#include <math.h>

#define B_    128
#define S_    100
#define D_    384
#define QK_   48
#define E_    768
#define LOCAL_ 384
#define NB_   8
#define NTOK_ 100
#define NPTS_ 256
#define M_    (B_*S_)   // 12800

static __device__ __forceinline__ float gelu_f(float x) {
    return 0.5f * x * (1.0f + erff(x * 0.70710678118654752440f));
}

// ---------------- LayerNorm over rows of 384 (wave per row) ----------------
__global__ __launch_bounds__(256)
void ln_rows(const float* __restrict__ X, const float* __restrict__ w,
             float* __restrict__ Y, int nrows)
{
    int row = blockIdx.x * 4 + (threadIdx.x >> 6);
    if (row >= nrows) return;
    int lane = threadIdx.x & 63;
    const float* x = X + (size_t)row * D_;
    float v[6]; float s = 0.f;
    #pragma unroll
    for (int t = 0; t < 6; ++t) { v[t] = x[lane + 64*t]; s += v[t]; }
    #pragma unroll
    for (int off = 32; off; off >>= 1) s += __shfl_xor(s, off);
    float mu = s * (1.f/(float)D_);
    float q = 0.f;
    #pragma unroll
    for (int t = 0; t < 6; ++t) { float d = v[t]-mu; q += d*d; }
    #pragma unroll
    for (int off = 32; off; off >>= 1) q += __shfl_xor(q, off);
    float rs = rsqrtf(q * (1.f/(float)D_) + 1e-5f);
    float* y = Y + (size_t)row * D_;
    #pragma unroll
    for (int t = 0; t < 6; ++t) y[lane + 64*t] = (v[t]-mu)*rs*w[lane + 64*t];
}

// ------------- gather emb[q] + LayerNorm -------------
__global__ __launch_bounds__(256)
void x_init(const int* __restrict__ qtok, const float* __restrict__ emb,
            const float* __restrict__ w, float* __restrict__ Y, int nrows)
{
    int row = blockIdx.x * 4 + (threadIdx.x >> 6);
    if (row >= nrows) return;
    int lane = threadIdx.x & 63;
    const float* x = emb + (size_t)qtok[row] * D_;
    float v[6]; float s = 0.f;
    #pragma unroll
    for (int t = 0; t < 6; ++t) { v[t] = x[lane + 64*t]; s += v[t]; }
    #pragma unroll
    for (int off = 32; off; off >>= 1) s += __shfl_xor(s, off);
    float mu = s * (1.f/(float)D_);
    float q = 0.f;
    #pragma unroll
    for (int t = 0; t < 6; ++t) { float d = v[t]-mu; q += d*d; }
    #pragma unroll
    for (int off = 32; off; off >>= 1) q += __shfl_xor(q, off);
    float rs = rsqrtf(q * (1.f/(float)D_) + 1e-5f);
    float* y = Y + (size_t)row * D_;
    #pragma unroll
    for (int t = 0; t < 6; ++t) y[lane + 64*t] = (v[t]-mu)*rs*w[lane + 64*t];
}

// ------------- generic tiled GEMM: C[M,N] = [A1|A2](M,K) @ W(N,K)^T -------------
// A cols [0,K1) from A1 (ld lda1), cols [K1,K) from A2 (ld lda2). accum: C += result.
// M must be a multiple of 64; K a multiple of 16. N arbitrary (guarded).
#define TILE 64
#define BKK  16

__global__ __launch_bounds__(256)
void gemm_bt(const float* __restrict__ A1, int lda1, int K1,
             const float* __restrict__ A2, int lda2,
             const float* __restrict__ W,
             float* __restrict__ C, int ldc,
             int M, int N, int K, int accum)
{
    __shared__ __align__(16) float As[BKK][TILE+4];
    __shared__ __align__(16) float Bs[BKK][TILE+4];
    int bx = blockIdx.x, by = blockIdx.y;
    int tid = threadIdx.x;
    int tx = tid & 15, ty = tid >> 4;
    int row0 = by*TILE, col0 = bx*TILE;
    float acc[4][4] = {};
    for (int k0 = 0; k0 < K; k0 += BKK) {
        #pragma unroll
        for (int i = 0; i < 4; ++i) {
            int idx = tid + i*256;
            int r = idx >> 4, k = idx & 15;
            int gk = k0 + k, gr = row0 + r;
            float v;
            if (gk < K1) v = A1[(size_t)gr*lda1 + gk];
            else         v = A2[(size_t)gr*lda2 + (gk - K1)];
            As[k][r] = v;
        }
        #pragma unroll
        for (int i = 0; i < 4; ++i) {
            int idx = tid + i*256;
            int n = idx >> 4, k = idx & 15;
            int gn = col0 + n;
            Bs[k][n] = (gn < N) ? W[(size_t)gn*K + k0 + k] : 0.0f;
        }
        __syncthreads();
        #pragma unroll
        for (int kk = 0; kk < BKK; ++kk) {
            float4 a4 = *reinterpret_cast<const float4*>(&As[kk][ty*4]);
            float4 b4 = *reinterpret_cast<const float4*>(&Bs[kk][tx*4]);
            float a[4] = {a4.x,a4.y,a4.z,a4.w};
            float b[4] = {b4.x,b4.y,b4.z,b4.w};
            #pragma unroll
            for (int i = 0; i < 4; ++i)
                #pragma unroll
                for (int j = 0; j < 4; ++j)
                    acc[i][j] += a[i]*b[j];
        }
        __syncthreads();
    }
    #pragma unroll
    for (int i = 0; i < 4; ++i) {
        int r = row0 + ty*4 + i;
        #pragma unroll
        for (int j = 0; j < 4; ++j) {
            int c = col0 + tx*4 + j;
            if (c < N) {
                size_t off = (size_t)r*ldc + c;
                C[off] = accum ? (C[off] + acc[i][j]) : acc[i][j];
            }
        }
    }
}

// ------------- paired GEMM with GEGLU epilogue: Out = (A@W1^T) * gelu(A@W2^T) -------------
__global__ __launch_bounds__(256)
void gemm_geglu(const float* __restrict__ A, int lda,
                const float* __restrict__ W1, const float* __restrict__ W2,
                float* __restrict__ Out, int ldo,
                int M, int N, int K)
{
    __shared__ __align__(16) float As [BKK][TILE+4];
    __shared__ __align__(16) float B1s[BKK][TILE+4];
    __shared__ __align__(16) float B2s[BKK][TILE+4];
    int bx = blockIdx.x, by = blockIdx.y;
    int tid = threadIdx.x;
    int tx = tid & 15, ty = tid >> 4;
    int row0 = by*TILE, col0 = bx*TILE;
    float acc1[4][4] = {}, acc2[4][4] = {};
    for (int k0 = 0; k0 < K; k0 += BKK) {
        #pragma unroll
        for (int i = 0; i < 4; ++i) {
            int idx = tid + i*256;
            int r = idx >> 4, k = idx & 15;
            As[k][r] = A[(size_t)(row0 + r)*lda + k0 + k];
        }
        #pragma unroll
        for (int i = 0; i < 4; ++i) {
            int idx = tid + i*256;
            int n = idx >> 4, k = idx & 15;
            int gn = col0 + n;
            B1s[k][n] = (gn < N) ? W1[(size_t)gn*K + k0 + k] : 0.0f;
            B2s[k][n] = (gn < N) ? W2[(size_t)gn*K + k0 + k] : 0.0f;
        }
        __syncthreads();
        #pragma unroll
        for (int kk = 0; kk < BKK; ++kk) {
            float4 a4 = *reinterpret_cast<const float4*>(&As[kk][ty*4]);
            float4 b14 = *reinterpret_cast<const float4*>(&B1s[kk][tx*4]);
            float4 b24 = *reinterpret_cast<const float4*>(&B2s[kk][tx*4]);
            float a[4] = {a4.x,a4.y,a4.z,a4.w};
            float b1[4] = {b14.x,b14.y,b14.z,b14.w};
            float b2[4] = {b24.x,b24.y,b24.z,b24.w};
            #pragma unroll
            for (int i = 0; i < 4; ++i)
                #pragma unroll
                for (int j = 0; j < 4; ++j) {
                    acc1[i][j] += a[i]*b1[j];
                    acc2[i][j] += a[i]*b2[j];
                }
        }
        __syncthreads();
    }
    #pragma unroll
    for (int i = 0; i < 4; ++i) {
        int r = row0 + ty*4 + i;
        #pragma unroll
        for (int j = 0; j < 4; ++j) {
            int c = col0 + tx*4 + j;
            if (c < N)
                Out[(size_t)r*ldo + c] = acc1[i][j] * gelu_f(acc2[i][j]);
        }
    }
}

// ------------- attention 1: causal, linear positional bias -------------
// qk: [M][96] (qr | kr), v = gegl cols [384,768), out: [M][384]
__global__ __launch_bounds__(256)
void attn1(const float* __restrict__ qk, const float* __restrict__ gegl,
           const float* __restrict__ bm, int blk,
           float* __restrict__ out)
{
    __shared__ float qrs[S_][QK_+1];
    __shared__ float krs[S_][QK_+1];
    __shared__ float ps[4][128];
    int b = blockIdx.x, tid = threadIdx.x;
    for (int idx = tid; idx < S_*QK_; idx += 256) {
        int r = idx / QK_, c = idx % QK_;
        const float* base = qk + ((size_t)(b*S_ + r))*96;
        qrs[r][c] = base[c];
        krs[r][c] = base[48 + c];
    }
    __syncthreads();
    float bmv = bm[blk];
    float sp = (bmv > 20.f) ? bmv : log1pf(expf(bmv));
    const float scale = 0.14433756729740643f;
    int w = tid >> 6, lane = tid & 63;
    const float* vbase = gegl + ((size_t)b*S_)*E_ + LOCAL_;
    for (int i = w; i < S_; i += 4) {
        int j1 = lane, j2 = lane + 64;
        float s1 = -1e30f, s2 = -1e30f;
        if (j1 <= i) {
            float acc = 0.f;
            #pragma unroll
            for (int l = 0; l < QK_; ++l) acc += qrs[i][l]*krs[j1][l];
            s1 = acc*scale + sp*(float)(j1 - i);
        }
        if (j2 <= i) {
            float acc = 0.f;
            #pragma unroll
            for (int l = 0; l < QK_; ++l) acc += qrs[i][l]*krs[j2][l];
            s2 = acc*scale + sp*(float)(j2 - i);
        }
        float m = fmaxf(s1, s2);
        #pragma unroll
        for (int off = 32; off; off >>= 1) m = fmaxf(m, __shfl_xor(m, off));
        float p1 = (j1 <= i) ? expf(s1 - m) : 0.f;
        float p2 = (j2 <= i) ? expf(s2 - m) : 0.f;
        float sum = p1 + p2;
        #pragma unroll
        for (int off = 32; off; off >>= 1) sum += __shfl_xor(sum, off);
        float inv = 1.f / sum;
        ps[w][j1] = p1 * inv;
        ps[w][j2] = p2 * inv;
        float acc[6] = {};
        for (int j = 0; j <= i; ++j) {
            float pj = ps[w][j];
            const float* vr = vbase + (size_t)j*E_;
            #pragma unroll
            for (int t = 0; t < 6; ++t) acc[t] += pj * vr[lane + 64*t];
        }
        float* o = out + ((size_t)(b*S_ + i))*D_;
        #pragma unroll
        for (int t = 0; t < 6; ++t) o[lane + 64*t] = acc[t];
    }
}

// ------------- P1/P2 = pt_emb @ Wkv halves -------------
__global__ __launch_bounds__(256)
void pk_proj(const float* __restrict__ pt_emb, const float* __restrict__ Wkv,
             float* __restrict__ P12)
{
    int e = blockIdx.x*256 + threadIdx.x;
    if (e >= 2*NTOK_*816) return;
    int half = e / (NTOK_*816);
    int rem  = e % (NTOK_*816);
    int t = rem / 816, c = rem % 816;
    const float* x = pt_emb + (size_t)t*192;
    const float* wv = Wkv + (size_t)c*384 + half*192;
    float s = 0.f;
    for (int k = 0; k < 192; ++k) s += x[k]*wv[k];
    P12[e] = s;
}

// ------------- gather pk rows, split into k2 and geglu'd values -------------
__global__ __launch_bounds__(256)
void pk_gather(const int* __restrict__ pts, const float* __restrict__ P12,
               float* __restrict__ k2, float* __restrict__ gv)
{
    int pair = blockIdx.x*4 + (threadIdx.x >> 6);   // b*256+j
    int lane = threadIdx.x & 63;
    const float* P1 = P12;
    const float* P2 = P12 + NTOK_*816;
    int t0 = pts[2*pair], t1 = pts[2*pair+1];
    const float* a = P1 + (size_t)t0*816;
    const float* c = P2 + (size_t)t1*816;
    if (lane < QK_) k2[(size_t)pair*QK_ + lane] = a[lane] + c[lane];
    #pragma unroll
    for (int t = 0; t < 6; ++t) {
        int i = lane + 64*t;
        float lin = a[48 + i] + c[48 + i];
        float pre = a[432 + i] + c[432 + i];
        gv[(size_t)pair*D_ + i] = lin * gelu_f(pre);
    }
}

// ------------- attention 2: 256 keys, no mask/bias -------------
__global__ __launch_bounds__(256)
void attn2(const float* __restrict__ q2, const float* __restrict__ k2,
           const float* __restrict__ gv, float* __restrict__ out)
{
    __shared__ float ks[NPTS_][QK_+1];
    __shared__ float ps[4][NPTS_];
    int b = blockIdx.x, tid = threadIdx.x;
    for (int idx = tid; idx < NPTS_*QK_; idx += 256) {
        int r = idx / QK_, c = idx % QK_;
        ks[r][c] = k2[((size_t)(b*NPTS_ + r))*QK_ + c];
    }
    __syncthreads();
    const float scale = 0.14433756729740643f;
    int w = tid >> 6, lane = tid & 63;
    const float* vb = gv + ((size_t)b*NPTS_)*D_;
    for (int i = w; i < S_; i += 4) {
        const float* qr = q2 + ((size_t)(b*S_ + i))*QK_;
        float s[4] = {0.f,0.f,0.f,0.f};
        for (int l = 0; l < QK_; ++l) {
            float ql = qr[l];
            #pragma unroll
            for (int r = 0; r < 4; ++r) s[r] += ql * ks[lane + 64*r][l];
        }
        #pragma unroll
        for (int r = 0; r < 4; ++r) s[r] *= scale;
        float m = fmaxf(fmaxf(s[0],s[1]), fmaxf(s[2],s[3]));
        #pragma unroll
        for (int off = 32; off; off >>= 1) m = fmaxf(m, __shfl_xor(m, off));
        float p[4]; float sum = 0.f;
        #pragma unroll
        for (int r = 0; r < 4; ++r) { p[r] = expf(s[r]-m); sum += p[r]; }
        #pragma unroll
        for (int off = 32; off; off >>= 1) sum += __shfl_xor(sum, off);
        float inv = 1.f / sum;
        #pragma unroll
        for (int r = 0; r < 4; ++r) ps[w][lane + 64*r] = p[r]*inv;
        float acc[6] = {};
        for (int j = 0; j < NPTS_; ++j) {
            float pj = ps[w][j];
            const float* vr = vb + (size_t)j*D_;
            #pragma unroll
            for (int t = 0; t < 6; ++t) acc[t] += pj * vr[lane + 64*t];
        }
        float* o = out + ((size_t)(b*S_ + i))*D_;
        #pragma unroll
        for (int t = 0; t < 6; ++t) o[lane + 64*t] = acc[t];
    }
}

extern "C" void kernel_launch(void* const* d_in, const int* in_sizes, int n_in,
                              void* d_out, int out_size, void* d_ws, size_t ws_size,
                              hipStream_t stream)
{
    const int*   qtok  = (const int*)d_in[0];
    const int*   pts   = (const int*)d_in[1];
    const float* emb   = (const float*)d_in[2];
    const float* ptemb = (const float*)d_in[3];
    const float* normw = (const float*)d_in[4];
    const float* outw  = (const float*)d_in[5];
    const float* ln1   = (const float*)d_in[6];
    const float* expand= (const float*)d_in[7];
    const float* proj1 = (const float*)d_in[8];
    const float* bm    = (const float*)d_in[9];
    const float* ln2   = (const float*)d_in[10];
    const float* Wq    = (const float*)d_in[11];
    const float* Wkv   = (const float*)d_in[12];
    const float* proj2 = (const float*)d_in[13];
    float* out = (float*)d_out;

    float* ws = (float*)d_ws;
    size_t off = 0;
    auto alloc = [&](size_t n){ float* p = ws + off; off += n; return p; };
    float* h     = alloc((size_t)M_*D_);
    float* n_    = alloc((size_t)M_*D_);
    float* qk1   = alloc((size_t)M_*96);       // also reused as qr2
    float* gegl  = alloc((size_t)M_*E_);       // also reused: gloc | P12 | k2
    float* attnb = alloc((size_t)M_*D_);
    float* gv    = alloc((size_t)B_*NPTS_*D_);

    float* qr2  = qk1;                 // [M][48], qk1 dead after attn1
    float* gloc = gegl;                // [M][384], gegl dead after p1
    float* P12  = gegl + (size_t)M_*D_;          // 2*100*816
    float* k2   = P12 + 2*NTOK_*816;             // [B*256][48]

    x_init<<<M_/4, 256, 0, stream>>>(qtok, emb, normw, h, M_);

    for (int blk = 0; blk < NB_; ++blk) {
        const float* We  = expand + (size_t)blk*1632*D_;
        const float* Wqb = Wq     + (size_t)blk*816*D_;

        ln_rows<<<M_/4, 256, 0, stream>>>(h, ln1 + blk*D_, n_, M_);
        // qr|kr : N=96
        gemm_bt<<<dim3(2,200), 256, 0, stream>>>(n_, D_, D_, nullptr, 0, We,
                                                 qk1, 96, M_, 96, D_, 0);
        // geglu = lin * gelu(pre) : N=768
        gemm_geglu<<<dim3(12,200), 256, 0, stream>>>(n_, D_, We + (size_t)96*D_,
                                                     We + (size_t)864*D_,
                                                     gegl, E_, M_, E_, D_);
        attn1<<<B_, 256, 0, stream>>>(qk1, gegl, bm, blk, attnb);
        // h += [geglu_local | attn] @ W_p1^T
        gemm_bt<<<dim3(6,200), 256, 0, stream>>>(gegl, E_, D_, attnb, D_,
                                                 proj1 + (size_t)blk*D_*E_,
                                                 h, D_, M_, D_, E_, 1);

        ln_rows<<<M_/4, 256, 0, stream>>>(h, ln2 + blk*D_, n_, M_);
        // qr2 : N=48
        gemm_bt<<<dim3(1,200), 256, 0, stream>>>(n_, D_, D_, nullptr, 0, Wqb,
                                                 qr2, QK_, M_, QK_, D_, 0);
        // g_local : N=384
        gemm_geglu<<<dim3(6,200), 256, 0, stream>>>(n_, D_, Wqb + (size_t)48*D_,
                                                    Wqb + (size_t)432*D_,
                                                    gloc, D_, M_, D_, D_);
        // pk path via P1/P2 trick
        pk_proj<<<(2*NTOK_*816 + 255)/256, 256, 0, stream>>>(ptemb,
                                                 Wkv + (size_t)blk*816*D_, P12);
        pk_gather<<<B_*NPTS_/4, 256, 0, stream>>>(pts, P12, k2, gv);
        attn2<<<B_, 256, 0, stream>>>(qr2, k2, gv, attnb);
        // h += [g_local | attn2] @ W_p2^T
        gemm_bt<<<dim3(6,200), 256, 0, stream>>>(gloc, D_, D_, attnb, D_,
                                                 proj2 + (size_t)blk*D_*E_,
                                                 h, D_, M_, D_, E_, 1);
    }

    ln_rows<<<M_/4, 256, 0, stream>>>(h, normw, n_, M_);
    gemm_bt<<<dim3(2,200), 256, 0, stream>>>(n_, D_, D_, nullptr, 0, outw,
                                             out, NTOK_, M_, NTOK_, D_, 0);
}

// Round 2
// 7922.069 us; speedup vs baseline: 1.5461x; 1.5461x over previous
//
#include <hip/hip_runtime.h>
#include <hip/hip_bf16.h>
#include <math.h>

#define B_    128
#define S_    100
#define D_    384
#define QK_   48
#define E_    768
#define LOCAL_ 384
#define NB_   8
#define NTOK_ 100
#define NPTS_ 256
#define M_    (B_*S_)   // 12800

static __device__ __forceinline__ float gelu_f(float x) {
    return 0.5f * x * (1.0f + erff(x * 0.70710678118654752440f));
}

// ---------------- LayerNorm over rows of 384 (wave per row) ----------------
__global__ __launch_bounds__(256)
void ln_rows(const float* __restrict__ X, const float* __restrict__ w,
             float* __restrict__ Y, int nrows)
{
    int row = blockIdx.x * 4 + (threadIdx.x >> 6);
    if (row >= nrows) return;
    int lane = threadIdx.x & 63;
    const float* x = X + (size_t)row * D_;
    float v[6]; float s = 0.f;
    #pragma unroll
    for (int t = 0; t < 6; ++t) { v[t] = x[lane + 64*t]; s += v[t]; }
    #pragma unroll
    for (int off = 32; off; off >>= 1) s += __shfl_xor(s, off);
    float mu = s * (1.f/(float)D_);
    float q = 0.f;
    #pragma unroll
    for (int t = 0; t < 6; ++t) { float d = v[t]-mu; q += d*d; }
    #pragma unroll
    for (int off = 32; off; off >>= 1) q += __shfl_xor(q, off);
    float rs = rsqrtf(q * (1.f/(float)D_) + 1e-5f);
    float* y = Y + (size_t)row * D_;
    #pragma unroll
    for (int t = 0; t < 6; ++t) y[lane + 64*t] = (v[t]-mu)*rs*w[lane + 64*t];
}

// ------------- gather emb[q] + LayerNorm -------------
__global__ __launch_bounds__(256)
void x_init(const int* __restrict__ qtok, const float* __restrict__ emb,
            const float* __restrict__ w, float* __restrict__ Y, int nrows)
{
    int row = blockIdx.x * 4 + (threadIdx.x >> 6);
    if (row >= nrows) return;
    int lane = threadIdx.x & 63;
    const float* x = emb + (size_t)qtok[row] * D_;
    float v[6]; float s = 0.f;
    #pragma unroll
    for (int t = 0; t < 6; ++t) { v[t] = x[lane + 64*t]; s += v[t]; }
    #pragma unroll
    for (int off = 32; off; off >>= 1) s += __shfl_xor(s, off);
    float mu = s * (1.f/(float)D_);
    float q = 0.f;
    #pragma unroll
    for (int t = 0; t < 6; ++t) { float d = v[t]-mu; q += d*d; }
    #pragma unroll
    for (int off = 32; off; off >>= 1) q += __shfl_xor(q, off);
    float rs = rsqrtf(q * (1.f/(float)D_) + 1e-5f);
    float* y = Y + (size_t)row * D_;
    #pragma unroll
    for (int t = 0; t < 6; ++t) y[lane + 64*t] = (v[t]-mu)*rs*w[lane + 64*t];
}

// ------------- generic tiled GEMM: C[M,N] = [A1|A2](M,K) @ W(N,K)^T -------------
#define TILE 64
#define BKK  16

__global__ __launch_bounds__(256)
void gemm_bt(const float* __restrict__ A1, int lda1, int K1,
             const float* __restrict__ A2, int lda2,
             const float* __restrict__ W,
             float* __restrict__ C, int ldc,
             int M, int N, int K, int accum)
{
    __shared__ __align__(16) float As[BKK][TILE+4];
    __shared__ __align__(16) float Bs[BKK][TILE+4];
    int bx = blockIdx.x, by = blockIdx.y;
    int tid = threadIdx.x;
    int tx = tid & 15, ty = tid >> 4;
    int row0 = by*TILE, col0 = bx*TILE;
    float acc[4][4] = {};
    for (int k0 = 0; k0 < K; k0 += BKK) {
        #pragma unroll
        for (int i = 0; i < 4; ++i) {
            int idx = tid + i*256;
            int r = idx >> 4, k = idx & 15;
            int gk = k0 + k, gr = row0 + r;
            float v;
            if (gk < K1) v = A1[(size_t)gr*lda1 + gk];
            else         v = A2[(size_t)gr*lda2 + (gk - K1)];
            As[k][r] = v;
        }
        #pragma unroll
        for (int i = 0; i < 4; ++i) {
            int idx = tid + i*256;
            int n = idx >> 4, k = idx & 15;
            int gn = col0 + n;
            Bs[k][n] = (gn < N) ? W[(size_t)gn*K + k0 + k] : 0.0f;
        }
        __syncthreads();
        #pragma unroll
        for (int kk = 0; kk < BKK; ++kk) {
            float4 a4 = *reinterpret_cast<const float4*>(&As[kk][ty*4]);
            float4 b4 = *reinterpret_cast<const float4*>(&Bs[kk][tx*4]);
            float a[4] = {a4.x,a4.y,a4.z,a4.w};
            float b[4] = {b4.x,b4.y,b4.z,b4.w};
            #pragma unroll
            for (int i = 0; i < 4; ++i)
                #pragma unroll
                for (int j = 0; j < 4; ++j)
                    acc[i][j] += a[i]*b[j];
        }
        __syncthreads();
    }
    #pragma unroll
    for (int i = 0; i < 4; ++i) {
        int r = row0 + ty*4 + i;
        #pragma unroll
        for (int j = 0; j < 4; ++j) {
            int c = col0 + tx*4 + j;
            if (c < N) {
                size_t off = (size_t)r*ldc + c;
                C[off] = accum ? (C[off] + acc[i][j]) : acc[i][j];
            }
        }
    }
}

// ------------- paired GEMM with GEGLU epilogue: Out = (A@W1^T) * gelu(A@W2^T) -------------
__global__ __launch_bounds__(256)
void gemm_geglu(const float* __restrict__ A, int lda,
                const float* __restrict__ W1, const float* __restrict__ W2,
                float* __restrict__ Out, int ldo,
                int M, int N, int K)
{
    __shared__ __align__(16) float As [BKK][TILE+4];
    __shared__ __align__(16) float B1s[BKK][TILE+4];
    __shared__ __align__(16) float B2s[BKK][TILE+4];
    int bx = blockIdx.x, by = blockIdx.y;
    int tid = threadIdx.x;
    int tx = tid & 15, ty = tid >> 4;
    int row0 = by*TILE, col0 = bx*TILE;
    float acc1[4][4] = {}, acc2[4][4] = {};
    for (int k0 = 0; k0 < K; k0 += BKK) {
        #pragma unroll
        for (int i = 0; i < 4; ++i) {
            int idx = tid + i*256;
            int r = idx >> 4, k = idx & 15;
            As[k][r] = A[(size_t)(row0 + r)*lda + k0 + k];
        }
        #pragma unroll
        for (int i = 0; i < 4; ++i) {
            int idx = tid + i*256;
            int n = idx >> 4, k = idx & 15;
            int gn = col0 + n;
            B1s[k][n] = (gn < N) ? W1[(size_t)gn*K + k0 + k] : 0.0f;
            B2s[k][n] = (gn < N) ? W2[(size_t)gn*K + k0 + k] : 0.0f;
        }
        __syncthreads();
        #pragma unroll
        for (int kk = 0; kk < BKK; ++kk) {
            float4 a4 = *reinterpret_cast<const float4*>(&As[kk][ty*4]);
            float4 b14 = *reinterpret_cast<const float4*>(&B1s[kk][tx*4]);
            float4 b24 = *reinterpret_cast<const float4*>(&B2s[kk][tx*4]);
            float a[4] = {a4.x,a4.y,a4.z,a4.w};
            float b1[4] = {b14.x,b14.y,b14.z,b14.w};
            float b2[4] = {b24.x,b24.y,b24.z,b24.w};
            #pragma unroll
            for (int i = 0; i < 4; ++i)
                #pragma unroll
                for (int j = 0; j < 4; ++j) {
                    acc1[i][j] += a[i]*b1[j];
                    acc2[i][j] += a[i]*b2[j];
                }
        }
        __syncthreads();
    }
    #pragma unroll
    for (int i = 0; i < 4; ++i) {
        int r = row0 + ty*4 + i;
        #pragma unroll
        for (int j = 0; j < 4; ++j) {
            int c = col0 + tx*4 + j;
            if (c < N)
                Out[(size_t)r*ldo + c] = acc1[i][j] * gelu_f(acc2[i][j]);
        }
    }
}

// ------------- batched GEMM (no transpose): C[b] = A[b](M x K) @ B[b](Kv x 384) -------------
// A zero-padded logically for rows >= M; B rows >= Kv treated as zero.
__global__ __launch_bounds__(256)
void gemm_nn_b(const float* __restrict__ A, int lda, long sA,
               const float* __restrict__ Bv, int ldb, long sB,
               float* __restrict__ C, int ldc, long sC,
               int M, int K, int Kv)
{
    const float* Ab = A  + (size_t)blockIdx.z * sA;
    const float* Bb = Bv + (size_t)blockIdx.z * sB;
    float*       Cb = C  + (size_t)blockIdx.z * sC;
    __shared__ __align__(16) float As[BKK][TILE+4];
    __shared__ __align__(16) float Bs[BKK][TILE+4];
    int tid = threadIdx.x;
    int tx = tid & 15, ty = tid >> 4;
    int row0 = blockIdx.y*TILE, col0 = blockIdx.x*TILE;
    float acc[4][4] = {};
    for (int k0 = 0; k0 < K; k0 += BKK) {
        #pragma unroll
        for (int i = 0; i < 4; ++i) {
            int idx = tid + i*256;
            int r = idx >> 4, k = idx & 15;
            int gr = row0 + r;
            As[k][r] = (gr < M) ? Ab[(size_t)gr*lda + k0 + k] : 0.0f;
        }
        #pragma unroll
        for (int i = 0; i < 4; ++i) {
            int idx = tid + i*256;
            int n = idx & 63, k = idx >> 6;
            int gk = k0 + k;
            Bs[k][n] = (gk < Kv) ? Bb[(size_t)gk*ldb + col0 + n] : 0.0f;
        }
        __syncthreads();
        #pragma unroll
        for (int kk = 0; kk < BKK; ++kk) {
            float4 a4 = *reinterpret_cast<const float4*>(&As[kk][ty*4]);
            float4 b4 = *reinterpret_cast<const float4*>(&Bs[kk][tx*4]);
            float a[4] = {a4.x,a4.y,a4.z,a4.w};
            float b[4] = {b4.x,b4.y,b4.z,b4.w};
            #pragma unroll
            for (int i = 0; i < 4; ++i)
                #pragma unroll
                for (int j = 0; j < 4; ++j)
                    acc[i][j] += a[i]*b[j];
        }
        __syncthreads();
    }
    #pragma unroll
    for (int i = 0; i < 4; ++i) {
        int r = row0 + ty*4 + i;
        if (r < M) {
            #pragma unroll
            for (int j = 0; j < 4; ++j)
                Cb[(size_t)r*ldc + col0 + tx*4 + j] = acc[i][j];
        }
    }
}

// ------------- attention 1 scores: causal + linear positional bias -> normalized P -------------
// qk: [M][96] (qr|kr). P: [B][100][128], cols j>i and j>=100 are 0.
__global__ __launch_bounds__(256)
void attn1_score(const float* __restrict__ qk, const float* __restrict__ bm, int blk,
                 float* __restrict__ P)
{
    __shared__ float qrs[50][QK_];
    __shared__ float krs[S_][QK_+1];
    int b = blockIdx.x, r0 = blockIdx.y*50;
    int tid = threadIdx.x;
    for (int idx = tid; idx < 50*QK_; idx += 256) {
        int r = idx / QK_, c = idx % QK_;
        qrs[r][c] = qk[((size_t)(b*S_ + r0 + r))*96 + c];
    }
    for (int idx = tid; idx < S_*QK_; idx += 256) {
        int r = idx / QK_, c = idx % QK_;
        krs[r][c] = qk[((size_t)(b*S_ + r))*96 + 48 + c];
    }
    __syncthreads();
    float bmv = bm[blk];
    float sp = (bmv > 20.f) ? bmv : log1pf(expf(bmv));
    const float scale = 0.14433756729740643f;
    int w = tid >> 6, lane = tid & 63;
    for (int t = 0; t < 13; ++t) {
        int li = w + 4*t;
        if (li >= 50) break;
        int i = r0 + li;
        int j1 = lane, j2 = lane + 64;
        float s1 = -1e30f, s2 = -1e30f;
        if (j1 <= i) {
            float acc = 0.f;
            #pragma unroll
            for (int l = 0; l < QK_; ++l) acc += qrs[li][l]*krs[j1][l];
            s1 = acc*scale + sp*(float)(j1 - i);
        }
        if (j2 <= i) {
            float acc = 0.f;
            #pragma unroll
            for (int l = 0; l < QK_; ++l) acc += qrs[li][l]*krs[j2][l];
            s2 = acc*scale + sp*(float)(j2 - i);
        }
        float m = fmaxf(s1, s2);
        #pragma unroll
        for (int off = 32; off; off >>= 1) m = fmaxf(m, __shfl_xor(m, off));
        float p1 = (j1 <= i) ? expf(s1 - m) : 0.f;
        float p2 = (j2 <= i) ? expf(s2 - m) : 0.f;
        float sum = p1 + p2;
        #pragma unroll
        for (int off = 32; off; off >>= 1) sum += __shfl_xor(sum, off);
        float inv = 1.f / sum;
        float* prow = P + ((size_t)(b*S_) + i)*128;
        prow[j1] = p1*inv;
        prow[j2] = p2*inv;
    }
}

// ------------- attention 2 scores: 256 keys, no mask -> normalized P -------------
// P: [B][100][256]
__global__ __launch_bounds__(256)
void attn2_score(const float* __restrict__ q2, const float* __restrict__ k2,
                 float* __restrict__ P)
{
    __shared__ float ks[NPTS_][QK_+1];
    int b = blockIdx.x, r0 = blockIdx.y*20;
    int tid = threadIdx.x;
    for (int idx = tid; idx < NPTS_*QK_; idx += 256) {
        int r = idx / QK_, c = idx % QK_;
        ks[r][c] = k2[((size_t)(b*NPTS_ + r))*QK_ + c];
    }
    __syncthreads();
    const float scale = 0.14433756729740643f;
    int w = tid >> 6, lane = tid & 63;
    for (int t = 0; t < 5; ++t) {
        int i = r0 + w + 4*t;
        const float* qr = q2 + ((size_t)(b*S_ + i))*QK_;
        float s[4] = {0.f,0.f,0.f,0.f};
        for (int l = 0; l < QK_; ++l) {
            float ql = qr[l];
            #pragma unroll
            for (int r = 0; r < 4; ++r) s[r] += ql * ks[lane + 64*r][l];
        }
        #pragma unroll
        for (int r = 0; r < 4; ++r) s[r] *= scale;
        float m = fmaxf(fmaxf(s[0],s[1]), fmaxf(s[2],s[3]));
        #pragma unroll
        for (int off = 32; off; off >>= 1) m = fmaxf(m, __shfl_xor(m, off));
        float p[4]; float sum = 0.f;
        #pragma unroll
        for (int r = 0; r < 4; ++r) { p[r] = expf(s[r]-m); sum += p[r]; }
        #pragma unroll
        for (int off = 32; off; off >>= 1) sum += __shfl_xor(sum, off);
        float inv = 1.f / sum;
        float* prow = P + ((size_t)(b*S_) + i)*256;
        #pragma unroll
        for (int r = 0; r < 4; ++r) prow[lane + 64*r] = p[r]*inv;
    }
}

// ------------- P1/P2 = pt_emb @ Wkv halves -------------
__global__ __launch_bounds__(256)
void pk_proj(const float* __restrict__ pt_emb, const float* __restrict__ Wkv,
             float* __restrict__ P12)
{
    int e = blockIdx.x*256 + threadIdx.x;
    if (e >= 2*NTOK_*816) return;
    int half = e / (NTOK_*816);
    int rem  = e % (NTOK_*816);
    int t = rem / 816, c = rem % 816;
    const float* x = pt_emb + (size_t)t*192;
    const float* wv = Wkv + (size_t)c*384 + half*192;
    float s = 0.f;
    for (int k = 0; k < 192; ++k) s += x[k]*wv[k];
    P12[e] = s;
}

// ------------- gather pk rows, split into k2 and geglu'd values -------------
__global__ __launch_bounds__(256)
void pk_gather(const int* __restrict__ pts, const float* __restrict__ P12,
               float* __restrict__ k2, float* __restrict__ gv)
{
    int pair = blockIdx.x*4 + (threadIdx.x >> 6);   // b*256+j
    int lane = threadIdx.x & 63;
    const float* P1 = P12;
    const float* P2 = P12 + NTOK_*816;
    int t0 = pts[2*pair], t1 = pts[2*pair+1];
    const float* a = P1 + (size_t)t0*816;
    const float* c = P2 + (size_t)t1*816;
    if (lane < QK_) k2[(size_t)pair*QK_ + lane] = a[lane] + c[lane];
    #pragma unroll
    for (int t = 0; t < 6; ++t) {
        int i = lane + 64*t;
        float lin = a[48 + i] + c[48 + i];
        float pre = a[432 + i] + c[432 + i];
        gv[(size_t)pair*D_ + i] = lin * gelu_f(pre);
    }
}

extern "C" void kernel_launch(void* const* d_in, const int* in_sizes, int n_in,
                              void* d_out, int out_size, void* d_ws, size_t ws_size,
                              hipStream_t stream)
{
    const int*   qtok  = (const int*)d_in[0];
    const int*   pts   = (const int*)d_in[1];
    const float* emb   = (const float*)d_in[2];
    const float* ptemb = (const float*)d_in[3];
    const float* normw = (const float*)d_in[4];
    const float* outw  = (const float*)d_in[5];
    const float* ln1   = (const float*)d_in[6];
    const float* expand= (const float*)d_in[7];
    const float* proj1 = (const float*)d_in[8];
    const float* bm    = (const float*)d_in[9];
    const float* ln2   = (const float*)d_in[10];
    const float* Wq    = (const float*)d_in[11];
    const float* Wkv   = (const float*)d_in[12];
    const float* proj2 = (const float*)d_in[13];
    float* out = (float*)d_out;

    float* ws = (float*)d_ws;
    size_t off = 0;
    auto alloc = [&](size_t n){ float* p = ws + off; off += n; return p; };
    float* h     = alloc((size_t)M_*D_);
    float* n_    = alloc((size_t)M_*D_);       // also reused as P (attn probs)
    float* qk1   = alloc((size_t)M_*96);       // also reused as qr2
    float* gegl  = alloc((size_t)M_*E_);       // also reused: gloc | P12 | k2
    float* attnb = alloc((size_t)M_*D_);
    float* gv    = alloc((size_t)B_*NPTS_*D_);

    float* qr2  = qk1;                 // [M][48], qk1 dead after attn1 scores
    float* gloc = gegl;                // [M][384], gegl dead after p1
    float* P12  = gegl + (size_t)M_*D_;          // 2*100*816
    float* k2   = P12 + 2*NTOK_*816;             // [B*256][48]
    float* Pbuf = n_;                  // P: attn1 [B][100][128] / attn2 [B][100][256]
                                       // n_ is dead between the expand GEMMs and next ln_rows

    x_init<<<M_/4, 256, 0, stream>>>(qtok, emb, normw, h, M_);

    for (int blk = 0; blk < NB_; ++blk) {
        const float* We  = expand + (size_t)blk*1632*D_;
        const float* Wqb = Wq     + (size_t)blk*816*D_;

        ln_rows<<<M_/4, 256, 0, stream>>>(h, ln1 + blk*D_, n_, M_);
        // qr|kr : N=96
        gemm_bt<<<dim3(2,200), 256, 0, stream>>>(n_, D_, D_, nullptr, 0, We,
                                                 qk1, 96, M_, 96, D_, 0);
        // geglu = lin * gelu(pre) : N=768
        gemm_geglu<<<dim3(12,200), 256, 0, stream>>>(n_, D_, We + (size_t)96*D_,
                                                     We + (size_t)864*D_,
                                                     gegl, E_, M_, E_, D_);
        // attn1: scores -> P (aliases n_), then PV batched GEMM
        attn1_score<<<dim3(B_,2), 256, 0, stream>>>(qk1, bm, blk, Pbuf);
        gemm_nn_b<<<dim3(6,2,B_), 256, 0, stream>>>(Pbuf, 128, (long)S_*128,
                                                    gegl + LOCAL_, E_, (long)S_*E_,
                                                    attnb, D_, (long)S_*D_,
                                                    S_, 128, S_);
        // h += [geglu_local | attn] @ W_p1^T
        gemm_bt<<<dim3(6,200), 256, 0, stream>>>(gegl, E_, D_, attnb, D_,
                                                 proj1 + (size_t)blk*D_*E_,
                                                 h, D_, M_, D_, E_, 1);

        ln_rows<<<M_/4, 256, 0, stream>>>(h, ln2 + blk*D_, n_, M_);
        // qr2 : N=48
        gemm_bt<<<dim3(1,200), 256, 0, stream>>>(n_, D_, D_, nullptr, 0, Wqb,
                                                 qr2, QK_, M_, QK_, D_, 0);
        // g_local : N=384
        gemm_geglu<<<dim3(6,200), 256, 0, stream>>>(n_, D_, Wqb + (size_t)48*D_,
                                                    Wqb + (size_t)432*D_,
                                                    gloc, D_, M_, D_, D_);
        // pk path via P1/P2 trick
        pk_proj<<<(2*NTOK_*816 + 255)/256, 256, 0, stream>>>(ptemb,
                                                 Wkv + (size_t)blk*816*D_, P12);
        pk_gather<<<B_*NPTS_/4, 256, 0, stream>>>(pts, P12, k2, gv);
        // attn2: scores -> P (aliases n_), then PV batched GEMM
        attn2_score<<<dim3(B_,5), 256, 0, stream>>>(qr2, k2, Pbuf);
        gemm_nn_b<<<dim3(6,2,B_), 256, 0, stream>>>(Pbuf, 256, (long)S_*256,
                                                    gv, D_, (long)NPTS_*D_,
                                                    attnb, D_, (long)S_*D_,
                                                    S_, 256, 256);
        // h += [g_local | attn2] @ W_p2^T
        gemm_bt<<<dim3(6,200), 256, 0, stream>>>(gloc, D_, D_, attnb, D_,
                                                 proj2 + (size_t)blk*D_*E_,
                                                 h, D_, M_, D_, E_, 1);
    }

    ln_rows<<<M_/4, 256, 0, stream>>>(h, normw, n_, M_);
    gemm_bt<<<dim3(2,200), 256, 0, stream>>>(n_, D_, D_, nullptr, 0, outw,
                                             out, NTOK_, M_, NTOK_, D_, 0);
}

// Round 3
// 3920.941 us; speedup vs baseline: 3.1238x; 2.0205x over previous
//
#include <hip/hip_runtime.h>
#include <hip/hip_bf16.h>
#include <math.h>

#define B_    128
#define S_    100
#define D_    384
#define QK_   48
#define E_    768
#define LOCAL_ 384
#define NB_   8
#define NTOK_ 100
#define NPTS_ 256
#define M_    (B_*S_)   // 12800

typedef unsigned short ushort;
typedef __attribute__((ext_vector_type(8))) short  bf16x8;
typedef __attribute__((ext_vector_type(8))) unsigned short ushort8v;
typedef __attribute__((ext_vector_type(4))) float  f32x4;

static __device__ __forceinline__ float gelu_f(float x) {
    return 0.5f * x * (1.0f + erff(x * 0.70710678118654752440f));
}
// fp32 -> bf16 (round-to-nearest-even), bit-level
static __device__ __forceinline__ ushort f2b(float f) {
    union { float f; unsigned u; } x; x.f = f;
    unsigned r = x.u + 0x7FFFu + ((x.u >> 16) & 1u);
    return (ushort)(r >> 16);
}
static __device__ __forceinline__ float b2f(ushort u) {
    union { unsigned u; float f; } x; x.u = ((unsigned)u) << 16;
    return x.f;
}

// ---------------- LayerNorm: fp32 in -> bf16 hi/lo out ----------------
__global__ __launch_bounds__(256)
void ln_rows(const float* __restrict__ X, const float* __restrict__ w,
             ushort* __restrict__ Yh, ushort* __restrict__ Yl, int nrows)
{
    int row = blockIdx.x * 4 + (threadIdx.x >> 6);
    if (row >= nrows) return;
    int lane = threadIdx.x & 63;
    const float* x = X + (size_t)row * D_;
    float v[6]; float s = 0.f;
    #pragma unroll
    for (int t = 0; t < 6; ++t) { v[t] = x[lane + 64*t]; s += v[t]; }
    #pragma unroll
    for (int off = 32; off; off >>= 1) s += __shfl_xor(s, off);
    float mu = s * (1.f/(float)D_);
    float q = 0.f;
    #pragma unroll
    for (int t = 0; t < 6; ++t) { float d = v[t]-mu; q += d*d; }
    #pragma unroll
    for (int off = 32; off; off >>= 1) q += __shfl_xor(q, off);
    float rs = rsqrtf(q * (1.f/(float)D_) + 1e-5f);
    #pragma unroll
    for (int t = 0; t < 6; ++t) {
        float y = (v[t]-mu)*rs*w[lane + 64*t];
        ushort h = f2b(y);
        Yh[(size_t)row*D_ + lane + 64*t] = h;
        Yl[(size_t)row*D_ + lane + 64*t] = f2b(y - b2f(h));
    }
}

// ------------- gather emb[q] + LayerNorm -> fp32 h -------------
__global__ __launch_bounds__(256)
void x_init(const int* __restrict__ qtok, const float* __restrict__ emb,
            const float* __restrict__ w, float* __restrict__ Y, int nrows)
{
    int row = blockIdx.x * 4 + (threadIdx.x >> 6);
    if (row >= nrows) return;
    int lane = threadIdx.x & 63;
    const float* x = emb + (size_t)qtok[row] * D_;
    float v[6]; float s = 0.f;
    #pragma unroll
    for (int t = 0; t < 6; ++t) { v[t] = x[lane + 64*t]; s += v[t]; }
    #pragma unroll
    for (int off = 32; off; off >>= 1) s += __shfl_xor(s, off);
    float mu = s * (1.f/(float)D_);
    float q = 0.f;
    #pragma unroll
    for (int t = 0; t < 6; ++t) { float d = v[t]-mu; q += d*d; }
    #pragma unroll
    for (int off = 32; off; off >>= 1) q += __shfl_xor(q, off);
    float rs = rsqrtf(q * (1.f/(float)D_) + 1e-5f);
    float* y = Y + (size_t)row * D_;
    #pragma unroll
    for (int t = 0; t < 6; ++t) y[lane + 64*t] = (v[t]-mu)*rs*w[lane + 64*t];
}

// ------------- weight split: fp32 -> bf16 hi/lo (per-layer 4 matrices) -------------
#define WE_SZ  (1632*384)   // 626688
#define P1_SZ  (384*768)    // 294912
#define WQ_SZ  (816*384)    // 313344
#define P2_SZ  (384*768)
#define WTOT   (WE_SZ + P1_SZ + WQ_SZ + P2_SZ)  // 1529856

__global__ __launch_bounds__(256)
void wconv(const float* __restrict__ we, const float* __restrict__ p1,
           const float* __restrict__ wq, const float* __restrict__ p2,
           ushort* __restrict__ wh, ushort* __restrict__ wl)
{
    int i = blockIdx.x*256 + threadIdx.x;
    if (i >= WTOT) return;
    float v;
    if (i < WE_SZ) v = we[i];
    else if (i < WE_SZ+P1_SZ) v = p1[i - WE_SZ];
    else if (i < WE_SZ+P1_SZ+WQ_SZ) v = wq[i - WE_SZ - P1_SZ];
    else v = p2[i - WE_SZ - P1_SZ - WQ_SZ];
    ushort h = f2b(v);
    wh[i] = h; wl[i] = f2b(v - b2f(h));
}

__global__ __launch_bounds__(256)
void wconv1(const float* __restrict__ src, int n,
            ushort* __restrict__ wh, ushort* __restrict__ wl)
{
    int i = blockIdx.x*256 + threadIdx.x;
    if (i >= n) return;
    float v = src[i];
    ushort h = f2b(v);
    wh[i] = h; wl[i] = f2b(v - b2f(h));
}

// ------------- MFMA split-bf16 GEMM: C[M,N] = [A1|A2] @ W^T (+C optional) -------------
// A sources are bf16 hi/lo pairs, row-major [rows][lda]. W is split pair [N][K].
// Block tile 64x64, 4 waves of 32x32, K step 32.
__global__ __launch_bounds__(256)
void mm_bt(const ushort* __restrict__ A1h, const ushort* __restrict__ A1l, int lda1, int K1,
           const ushort* __restrict__ A2h, const ushort* __restrict__ A2l, int lda2,
           const ushort* __restrict__ Wgh, const ushort* __restrict__ Wgl,
           float* __restrict__ C, int ldc, int N, int K, int accum)
{
    __shared__ ushort Ah[64][32], Al[64][32], Wh[64][32], Wl[64][32];
    int tid = threadIdx.x;
    int row0 = blockIdx.y*64, col0 = blockIdx.x*64;
    int srow = tid >> 2, sseg = (tid & 3) * 8;
    int arow = row0 + srow;
    int wrow = col0 + srow;
    bool wok = wrow < N;
    int wid = tid >> 6, lane = tid & 63;
    int wr = wid >> 1, wc = wid & 1;
    int fr = lane & 15, fg = lane >> 4;
    f32x4 acc[2][2] = {};
    for (int k0 = 0; k0 < K; k0 += 32) {
        ushort8v va, vb, vc = {}, vd = {};
        if (k0 < K1) {
            va = *(const ushort8v*)(A1h + (size_t)arow*lda1 + k0 + sseg);
            vb = *(const ushort8v*)(A1l + (size_t)arow*lda1 + k0 + sseg);
        } else {
            va = *(const ushort8v*)(A2h + (size_t)arow*lda2 + (k0-K1) + sseg);
            vb = *(const ushort8v*)(A2l + (size_t)arow*lda2 + (k0-K1) + sseg);
        }
        if (wok) {
            vc = *(const ushort8v*)(Wgh + (size_t)wrow*K + k0 + sseg);
            vd = *(const ushort8v*)(Wgl + (size_t)wrow*K + k0 + sseg);
        }
        __syncthreads();
        *(ushort8v*)&Ah[srow][sseg] = va;
        *(ushort8v*)&Al[srow][sseg] = vb;
        *(ushort8v*)&Wh[srow][sseg] = vc;
        *(ushort8v*)&Wl[srow][sseg] = vd;
        __syncthreads();
        bf16x8 a_h[2], a_l[2], b_h[2], b_l[2];
        #pragma unroll
        for (int s = 0; s < 2; ++s) {
            a_h[s] = *(const bf16x8*)&Ah[wr*32 + s*16 + fr][fg*8];
            a_l[s] = *(const bf16x8*)&Al[wr*32 + s*16 + fr][fg*8];
            b_h[s] = *(const bf16x8*)&Wh[wc*32 + s*16 + fr][fg*8];
            b_l[s] = *(const bf16x8*)&Wl[wc*32 + s*16 + fr][fg*8];
        }
        #pragma unroll
        for (int s = 0; s < 2; ++s)
            #pragma unroll
            for (int u = 0; u < 2; ++u)
                acc[s][u] = __builtin_amdgcn_mfma_f32_16x16x32_bf16(a_h[s], b_h[u], acc[s][u], 0,0,0);
        #pragma unroll
        for (int s = 0; s < 2; ++s)
            #pragma unroll
            for (int u = 0; u < 2; ++u)
                acc[s][u] = __builtin_amdgcn_mfma_f32_16x16x32_bf16(a_h[s], b_l[u], acc[s][u], 0,0,0);
        #pragma unroll
        for (int s = 0; s < 2; ++s)
            #pragma unroll
            for (int u = 0; u < 2; ++u)
                acc[s][u] = __builtin_amdgcn_mfma_f32_16x16x32_bf16(a_l[s], b_h[u], acc[s][u], 0,0,0);
    }
    #pragma unroll
    for (int s = 0; s < 2; ++s) {
        int r = row0 + wr*32 + s*16 + fg*4;
        #pragma unroll
        for (int u = 0; u < 2; ++u) {
            int c = col0 + wc*32 + u*16 + fr;
            if (c < N) {
                #pragma unroll
                for (int j = 0; j < 4; ++j) {
                    size_t o = (size_t)(r+j)*ldc + c;
                    C[o] = accum ? (C[o] + acc[s][u][j]) : acc[s][u][j];
                }
            }
        }
    }
}

// ------------- MFMA split-bf16 GEGLU GEMM: Out = (A@W1^T) * gelu(A@W2^T), bf16 hi/lo out -------------
__global__ __launch_bounds__(256)
void mm_geglu(const ushort* __restrict__ Agh, const ushort* __restrict__ Agl, int lda,
              const ushort* __restrict__ W1h, const ushort* __restrict__ W1l,
              const ushort* __restrict__ W2h, const ushort* __restrict__ W2l,
              ushort* __restrict__ Oh, ushort* __restrict__ Ol, int ldo,
              int N, int K)
{
    __shared__ ushort Ah[64][32], Al[64][32];
    __shared__ ushort X1h[64][32], X1l[64][32], X2h[64][32], X2l[64][32];
    int tid = threadIdx.x;
    int row0 = blockIdx.y*64, col0 = blockIdx.x*64;
    int srow = tid >> 2, sseg = (tid & 3) * 8;
    int arow = row0 + srow;
    int wrow = col0 + srow;
    int wid = tid >> 6, lane = tid & 63;
    int wr = wid >> 1, wc = wid & 1;
    int fr = lane & 15, fg = lane >> 4;
    f32x4 acc1[2][2] = {}, acc2[2][2] = {};
    for (int k0 = 0; k0 < K; k0 += 32) {
        ushort8v va = *(const ushort8v*)(Agh + (size_t)arow*lda + k0 + sseg);
        ushort8v vb = *(const ushort8v*)(Agl + (size_t)arow*lda + k0 + sseg);
        ushort8v v1 = *(const ushort8v*)(W1h + (size_t)wrow*K + k0 + sseg);
        ushort8v v2 = *(const ushort8v*)(W1l + (size_t)wrow*K + k0 + sseg);
        ushort8v v3 = *(const ushort8v*)(W2h + (size_t)wrow*K + k0 + sseg);
        ushort8v v4 = *(const ushort8v*)(W2l + (size_t)wrow*K + k0 + sseg);
        __syncthreads();
        *(ushort8v*)&Ah[srow][sseg]  = va;
        *(ushort8v*)&Al[srow][sseg]  = vb;
        *(ushort8v*)&X1h[srow][sseg] = v1;
        *(ushort8v*)&X1l[srow][sseg] = v2;
        *(ushort8v*)&X2h[srow][sseg] = v3;
        *(ushort8v*)&X2l[srow][sseg] = v4;
        __syncthreads();
        bf16x8 a_h[2], a_l[2], b1h[2], b1l[2], b2h[2], b2l[2];
        #pragma unroll
        for (int s = 0; s < 2; ++s) {
            a_h[s] = *(const bf16x8*)&Ah[wr*32 + s*16 + fr][fg*8];
            a_l[s] = *(const bf16x8*)&Al[wr*32 + s*16 + fr][fg*8];
            b1h[s] = *(const bf16x8*)&X1h[wc*32 + s*16 + fr][fg*8];
            b1l[s] = *(const bf16x8*)&X1l[wc*32 + s*16 + fr][fg*8];
            b2h[s] = *(const bf16x8*)&X2h[wc*32 + s*16 + fr][fg*8];
            b2l[s] = *(const bf16x8*)&X2l[wc*32 + s*16 + fr][fg*8];
        }
        #pragma unroll
        for (int s = 0; s < 2; ++s)
            #pragma unroll
            for (int u = 0; u < 2; ++u) {
                acc1[s][u] = __builtin_amdgcn_mfma_f32_16x16x32_bf16(a_h[s], b1h[u], acc1[s][u], 0,0,0);
                acc2[s][u] = __builtin_amdgcn_mfma_f32_16x16x32_bf16(a_h[s], b2h[u], acc2[s][u], 0,0,0);
            }
        #pragma unroll
        for (int s = 0; s < 2; ++s)
            #pragma unroll
            for (int u = 0; u < 2; ++u) {
                acc1[s][u] = __builtin_amdgcn_mfma_f32_16x16x32_bf16(a_h[s], b1l[u], acc1[s][u], 0,0,0);
                acc2[s][u] = __builtin_amdgcn_mfma_f32_16x16x32_bf16(a_h[s], b2l[u], acc2[s][u], 0,0,0);
            }
        #pragma unroll
        for (int s = 0; s < 2; ++s)
            #pragma unroll
            for (int u = 0; u < 2; ++u) {
                acc1[s][u] = __builtin_amdgcn_mfma_f32_16x16x32_bf16(a_l[s], b1h[u], acc1[s][u], 0,0,0);
                acc2[s][u] = __builtin_amdgcn_mfma_f32_16x16x32_bf16(a_l[s], b2h[u], acc2[s][u], 0,0,0);
            }
    }
    #pragma unroll
    for (int s = 0; s < 2; ++s) {
        int r = row0 + wr*32 + s*16 + fg*4;
        #pragma unroll
        for (int u = 0; u < 2; ++u) {
            int c = col0 + wc*32 + u*16 + fr;
            #pragma unroll
            for (int j = 0; j < 4; ++j) {
                float g = acc1[s][u][j] * gelu_f(acc2[s][u][j]);
                ushort h = f2b(g);
                size_t o = (size_t)(r+j)*ldo + c;
                Oh[o] = h; Ol[o] = f2b(g - b2f(h));
            }
        }
    }
}

// ------------- PV batched GEMM (bf16 in, fp32 math, bf16 hi/lo out) -------------
#define TILE 64
#define BKK  16
__global__ __launch_bounds__(256)
void pv_b(const ushort* __restrict__ P, int ldp, long sP,
          const ushort* __restrict__ V, int ldv, long sV,
          ushort* __restrict__ Oh, ushort* __restrict__ Ol, int ldo, long sO,
          int Mrows, int K, int Kv)
{
    const ushort* Pb = P + (size_t)blockIdx.z * sP;
    const ushort* Vb = V + (size_t)blockIdx.z * sV;
    ushort* Ohb = Oh + (size_t)blockIdx.z * sO;
    ushort* Olb = Ol + (size_t)blockIdx.z * sO;
    __shared__ __align__(16) float As[BKK][TILE+4];
    __shared__ __align__(16) float Bs[BKK][TILE+4];
    int tid = threadIdx.x;
    int tx = tid & 15, ty = tid >> 4;
    int row0 = blockIdx.y*TILE, col0 = blockIdx.x*TILE;
    float acc[4][4] = {};
    for (int k0 = 0; k0 < K; k0 += BKK) {
        #pragma unroll
        for (int i = 0; i < 4; ++i) {
            int idx = tid + i*256;
            int r = idx >> 4, k = idx & 15;
            int gr = row0 + r;
            As[k][r] = (gr < Mrows) ? b2f(Pb[(size_t)gr*ldp + k0 + k]) : 0.0f;
        }
        #pragma unroll
        for (int i = 0; i < 4; ++i) {
            int idx = tid + i*256;
            int n = idx & 63, k = idx >> 6;
            int gk = k0 + k;
            Bs[k][n] = (gk < Kv) ? b2f(Vb[(size_t)gk*ldv + col0 + n]) : 0.0f;
        }
        __syncthreads();
        #pragma unroll
        for (int kk = 0; kk < BKK; ++kk) {
            float4 a4 = *reinterpret_cast<const float4*>(&As[kk][ty*4]);
            float4 b4 = *reinterpret_cast<const float4*>(&Bs[kk][tx*4]);
            float a[4] = {a4.x,a4.y,a4.z,a4.w};
            float b[4] = {b4.x,b4.y,b4.z,b4.w};
            #pragma unroll
            for (int i = 0; i < 4; ++i)
                #pragma unroll
                for (int j = 0; j < 4; ++j)
                    acc[i][j] += a[i]*b[j];
        }
        __syncthreads();
    }
    #pragma unroll
    for (int i = 0; i < 4; ++i) {
        int r = row0 + ty*4 + i;
        if (r < Mrows) {
            #pragma unroll
            for (int j = 0; j < 4; ++j) {
                float x = acc[i][j];
                ushort h = f2b(x);
                size_t o = (size_t)r*ldo + col0 + tx*4 + j;
                Ohb[o] = h; Olb[o] = f2b(x - b2f(h));
            }
        }
    }
}

// ------------- attention 1 scores -> normalized P (bf16) -------------
__global__ __launch_bounds__(256)
void attn1_score(const float* __restrict__ qk, const float* __restrict__ bm, int blk,
                 ushort* __restrict__ P)
{
    __shared__ float qrs[50][QK_];
    __shared__ float krs[S_][QK_+1];
    int b = blockIdx.x, r0 = blockIdx.y*50;
    int tid = threadIdx.x;
    for (int idx = tid; idx < 50*QK_; idx += 256) {
        int r = idx / QK_, c = idx % QK_;
        qrs[r][c] = qk[((size_t)(b*S_ + r0 + r))*96 + c];
    }
    for (int idx = tid; idx < S_*QK_; idx += 256) {
        int r = idx / QK_, c = idx % QK_;
        krs[r][c] = qk[((size_t)(b*S_ + r))*96 + 48 + c];
    }
    __syncthreads();
    float bmv = bm[blk];
    float sp = (bmv > 20.f) ? bmv : log1pf(expf(bmv));
    const float scale = 0.14433756729740643f;
    int w = tid >> 6, lane = tid & 63;
    for (int t = 0; t < 13; ++t) {
        int li = w + 4*t;
        if (li >= 50) break;
        int i = r0 + li;
        int j1 = lane, j2 = lane + 64;
        float s1 = -1e30f, s2 = -1e30f;
        if (j1 <= i) {
            float acc = 0.f;
            #pragma unroll
            for (int l = 0; l < QK_; ++l) acc += qrs[li][l]*krs[j1][l];
            s1 = acc*scale + sp*(float)(j1 - i);
        }
        if (j2 <= i) {
            float acc = 0.f;
            #pragma unroll
            for (int l = 0; l < QK_; ++l) acc += qrs[li][l]*krs[j2][l];
            s2 = acc*scale + sp*(float)(j2 - i);
        }
        float m = fmaxf(s1, s2);
        #pragma unroll
        for (int off = 32; off; off >>= 1) m = fmaxf(m, __shfl_xor(m, off));
        float p1 = (j1 <= i) ? expf(s1 - m) : 0.f;
        float p2 = (j2 <= i) ? expf(s2 - m) : 0.f;
        float sum = p1 + p2;
        #pragma unroll
        for (int off = 32; off; off >>= 1) sum += __shfl_xor(sum, off);
        float inv = 1.f / sum;
        ushort* prow = P + ((size_t)(b*S_) + i)*128;
        prow[j1] = f2b(p1*inv);
        prow[j2] = f2b(p2*inv);
    }
}

// ------------- attention 2 scores -> normalized P (bf16) -------------
__global__ __launch_bounds__(256)
void attn2_score(const float* __restrict__ q2, const float* __restrict__ k2,
                 ushort* __restrict__ P)
{
    __shared__ float ks[NPTS_][QK_+1];
    int b = blockIdx.x, r0 = blockIdx.y*20;
    int tid = threadIdx.x;
    for (int idx = tid; idx < NPTS_*QK_; idx += 256) {
        int r = idx / QK_, c = idx % QK_;
        ks[r][c] = k2[((size_t)(b*NPTS_ + r))*QK_ + c];
    }
    __syncthreads();
    const float scale = 0.14433756729740643f;
    int w = tid >> 6, lane = tid & 63;
    for (int t = 0; t < 5; ++t) {
        int i = r0 + w + 4*t;
        const float* qr = q2 + ((size_t)(b*S_ + i))*QK_;
        float s[4] = {0.f,0.f,0.f,0.f};
        for (int l = 0; l < QK_; ++l) {
            float ql = qr[l];
            #pragma unroll
            for (int r = 0; r < 4; ++r) s[r] += ql * ks[lane + 64*r][l];
        }
        #pragma unroll
        for (int r = 0; r < 4; ++r) s[r] *= scale;
        float m = fmaxf(fmaxf(s[0],s[1]), fmaxf(s[2],s[3]));
        #pragma unroll
        for (int off = 32; off; off >>= 1) m = fmaxf(m, __shfl_xor(m, off));
        float p[4]; float sum = 0.f;
        #pragma unroll
        for (int r = 0; r < 4; ++r) { p[r] = expf(s[r]-m); sum += p[r]; }
        #pragma unroll
        for (int off = 32; off; off >>= 1) sum += __shfl_xor(sum, off);
        float inv = 1.f / sum;
        ushort* prow = P + ((size_t)(b*S_) + i)*256;
        #pragma unroll
        for (int r = 0; r < 4; ++r) prow[lane + 64*r] = f2b(p[r]*inv);
    }
}

// ------------- P1/P2 = pt_emb @ Wkv halves (fp32) -------------
__global__ __launch_bounds__(256)
void pk_proj(const float* __restrict__ pt_emb, const float* __restrict__ Wkv,
             float* __restrict__ P12)
{
    int e = blockIdx.x*256 + threadIdx.x;
    if (e >= 2*NTOK_*816) return;
    int half = e / (NTOK_*816);
    int rem  = e % (NTOK_*816);
    int t = rem / 816, c = rem % 816;
    const float* x = pt_emb + (size_t)t*192;
    const float* wv = Wkv + (size_t)c*384 + half*192;
    float s = 0.f;
    for (int k = 0; k < 192; ++k) s += x[k]*wv[k];
    P12[e] = s;
}

// ------------- gather pk rows -> k2 (fp32), geglu'd values gv (bf16) -------------
__global__ __launch_bounds__(256)
void pk_gather(const int* __restrict__ pts, const float* __restrict__ P12,
               float* __restrict__ k2, ushort* __restrict__ gv)
{
    int pair = blockIdx.x*4 + (threadIdx.x >> 6);
    int lane = threadIdx.x & 63;
    const float* P1 = P12;
    const float* P2 = P12 + NTOK_*816;
    int t0 = pts[2*pair], t1 = pts[2*pair+1];
    const float* a = P1 + (size_t)t0*816;
    const float* c = P2 + (size_t)t1*816;
    if (lane < QK_) k2[(size_t)pair*QK_ + lane] = a[lane] + c[lane];
    #pragma unroll
    for (int t = 0; t < 6; ++t) {
        int i = lane + 64*t;
        float lin = a[48 + i] + c[48 + i];
        float pre = a[432 + i] + c[432 + i];
        gv[(size_t)pair*D_ + i] = f2b(lin * gelu_f(pre));
    }
}

extern "C" void kernel_launch(void* const* d_in, const int* in_sizes, int n_in,
                              void* d_out, int out_size, void* d_ws, size_t ws_size,
                              hipStream_t stream)
{
    const int*   qtok  = (const int*)d_in[0];
    const int*   pts   = (const int*)d_in[1];
    const float* emb   = (const float*)d_in[2];
    const float* ptemb = (const float*)d_in[3];
    const float* normw = (const float*)d_in[4];
    const float* outw  = (const float*)d_in[5];
    const float* ln1   = (const float*)d_in[6];
    const float* expand= (const float*)d_in[7];
    const float* proj1 = (const float*)d_in[8];
    const float* bm    = (const float*)d_in[9];
    const float* ln2   = (const float*)d_in[10];
    const float* Wq    = (const float*)d_in[11];
    const float* Wkv   = (const float*)d_in[12];
    const float* proj2 = (const float*)d_in[13];
    float* out = (float*)d_out;

    char* base = (char*)d_ws;
    size_t off = 0;
    auto alloc = [&](size_t bytes){ void* p = base + off; off += (bytes + 255) & ~(size_t)255; return p; };
    float*  h     = (float*) alloc((size_t)M_*D_*4);
    ushort* nhi   = (ushort*)alloc((size_t)M_*D_*2);
    ushort* nlo   = (ushort*)alloc((size_t)M_*D_*2);
    float*  qk1   = (float*) alloc((size_t)M_*96*4);     // qr2 aliases
    ushort* geglh = (ushort*)alloc((size_t)M_*E_*2);     // gloc_h aliases
    ushort* gegll = (ushort*)alloc((size_t)M_*E_*2);     // gloc_l aliases
    ushort* atbh  = (ushort*)alloc((size_t)M_*D_*2);
    ushort* atbl  = (ushort*)alloc((size_t)M_*D_*2);
    ushort* Pbuf  = (ushort*)alloc((size_t)M_*256*2);
    ushort* gv    = (ushort*)alloc((size_t)B_*NPTS_*D_*2);
    float*  P12   = (float*) alloc((size_t)2*NTOK_*816*4);
    float*  k2    = (float*) alloc((size_t)B_*NPTS_*QK_*4);
    ushort* wbh   = (ushort*)alloc((size_t)WTOT*2);
    ushort* wbl   = (ushort*)alloc((size_t)WTOT*2);

    float*  qr2   = qk1;
    ushort* gloch = geglh;
    ushort* glocl = gegll;

    // weight slice offsets inside wbuf
    const size_t oWE = 0;
    const size_t oP1 = WE_SZ;
    const size_t oWQ = WE_SZ + P1_SZ;
    const size_t oP2 = WE_SZ + P1_SZ + WQ_SZ;

    x_init<<<M_/4, 256, 0, stream>>>(qtok, emb, normw, h, M_);

    for (int blk = 0; blk < NB_; ++blk) {
        wconv<<<(WTOT+255)/256, 256, 0, stream>>>(
            expand + (size_t)blk*WE_SZ, proj1 + (size_t)blk*P1_SZ,
            Wq + (size_t)blk*WQ_SZ, proj2 + (size_t)blk*P2_SZ, wbh, wbl);

        ln_rows<<<M_/4, 256, 0, stream>>>(h, ln1 + blk*D_, nhi, nlo, M_);
        // qk : N=96, K=384  (W rows 0..95 of We)
        mm_bt<<<dim3(2, M_/64), 256, 0, stream>>>(nhi, nlo, D_, D_, nhi, nlo, D_,
            wbh + oWE, wbl + oWE, qk1, 96, 96, D_, 0);
        // geglu768 (W1 = We rows 96.., W2 = We rows 864..)
        mm_geglu<<<dim3(12, M_/64), 256, 0, stream>>>(nhi, nlo, D_,
            wbh + oWE + (size_t)96*D_,  wbl + oWE + (size_t)96*D_,
            wbh + oWE + (size_t)864*D_, wbl + oWE + (size_t)864*D_,
            geglh, gegll, E_, E_, D_);
        attn1_score<<<dim3(B_,2), 256, 0, stream>>>(qk1, bm, blk, Pbuf);
        pv_b<<<dim3(6,2,B_), 256, 0, stream>>>(Pbuf, 128, (long)S_*128,
            geglh + LOCAL_, E_, (long)S_*E_,
            atbh, atbl, D_, (long)S_*D_, S_, 128, S_);
        // h += [geglu_local | attn] @ W_p1^T   (A1 = gegl cols 0..383, A2 = attnb)
        mm_bt<<<dim3(6, M_/64), 256, 0, stream>>>(geglh, gegll, E_, D_, atbh, atbl, D_,
            wbh + oP1, wbl + oP1, h, D_, D_, E_, 1);

        ln_rows<<<M_/4, 256, 0, stream>>>(h, ln2 + blk*D_, nhi, nlo, M_);
        // qr2 : N=48
        mm_bt<<<dim3(1, M_/64), 256, 0, stream>>>(nhi, nlo, D_, D_, nhi, nlo, D_,
            wbh + oWQ, wbl + oWQ, qr2, QK_, QK_, D_, 0);
        // g_local geglu384 (W1 = Wq rows 48.., W2 = Wq rows 432..)
        mm_geglu<<<dim3(6, M_/64), 256, 0, stream>>>(nhi, nlo, D_,
            wbh + oWQ + (size_t)48*D_,  wbl + oWQ + (size_t)48*D_,
            wbh + oWQ + (size_t)432*D_, wbl + oWQ + (size_t)432*D_,
            gloch, glocl, D_, D_, D_);
        // pk path
        pk_proj<<<(2*NTOK_*816 + 255)/256, 256, 0, stream>>>(ptemb,
            Wkv + (size_t)blk*816*D_, P12);
        pk_gather<<<B_*NPTS_/4, 256, 0, stream>>>(pts, P12, k2, gv);
        attn2_score<<<dim3(B_,5), 256, 0, stream>>>(qr2, k2, Pbuf);
        pv_b<<<dim3(6,2,B_), 256, 0, stream>>>(Pbuf, 256, (long)S_*256,
            gv, D_, (long)NPTS_*D_,
            atbh, atbl, D_, (long)S_*D_, S_, 256, 256);
        // h += [g_local | attn2] @ W_p2^T
        mm_bt<<<dim3(6, M_/64), 256, 0, stream>>>(gloch, glocl, D_, D_, atbh, atbl, D_,
            wbh + oP2, wbl + oP2, h, D_, D_, E_, 1);
    }

    ln_rows<<<M_/4, 256, 0, stream>>>(h, normw, nhi, nlo, M_);
    wconv1<<<(NTOK_*D_ + 255)/256, 256, 0, stream>>>(outw, NTOK_*D_, wbh, wbl);
    mm_bt<<<dim3(2, M_/64), 256, 0, stream>>>(nhi, nlo, D_, D_, nhi, nlo, D_,
        wbh, wbl, out, NTOK_, NTOK_, D_, 0);
}

// Round 4
// 3063.788 us; speedup vs baseline: 3.9977x; 1.2798x over previous
//
#include <hip/hip_runtime.h>
#include <hip/hip_bf16.h>
#include <math.h>

#define B_    128
#define S_    100
#define D_    384
#define QK_   48
#define E_    768
#define LOCAL_ 384
#define NB_   8
#define NTOK_ 100
#define NPTS_ 256
#define M_    (B_*S_)   // 12800

typedef unsigned short ushort;
typedef __attribute__((ext_vector_type(8))) short  bf16x8;
typedef __attribute__((ext_vector_type(8))) unsigned short ushort8v;
typedef __attribute__((ext_vector_type(4))) float  f32x4;

static __device__ __forceinline__ float gelu_f(float x) {
    return 0.5f * x * (1.0f + erff(x * 0.70710678118654752440f));
}
// fp32 -> bf16 (round-to-nearest-even), bit-level
static __device__ __forceinline__ ushort f2b(float f) {
    union { float f; unsigned u; } x; x.f = f;
    unsigned r = x.u + 0x7FFFu + ((x.u >> 16) & 1u);
    return (ushort)(r >> 16);
}
static __device__ __forceinline__ float b2f(ushort u) {
    union { unsigned u; float f; } x; x.u = ((unsigned)u) << 16;
    return x.f;
}

// ---------------- LayerNorm: fp32 in -> bf16 hi/lo out ----------------
__global__ __launch_bounds__(256)
void ln_rows(const float* __restrict__ X, const float* __restrict__ w,
             ushort* __restrict__ Yh, ushort* __restrict__ Yl, int nrows)
{
    int row = blockIdx.x * 4 + (threadIdx.x >> 6);
    if (row >= nrows) return;
    int lane = threadIdx.x & 63;
    const float* x = X + (size_t)row * D_;
    float v[6]; float s = 0.f;
    #pragma unroll
    for (int t = 0; t < 6; ++t) { v[t] = x[lane + 64*t]; s += v[t]; }
    #pragma unroll
    for (int off = 32; off; off >>= 1) s += __shfl_xor(s, off);
    float mu = s * (1.f/(float)D_);
    float q = 0.f;
    #pragma unroll
    for (int t = 0; t < 6; ++t) { float d = v[t]-mu; q += d*d; }
    #pragma unroll
    for (int off = 32; off; off >>= 1) q += __shfl_xor(q, off);
    float rs = rsqrtf(q * (1.f/(float)D_) + 1e-5f);
    #pragma unroll
    for (int t = 0; t < 6; ++t) {
        float y = (v[t]-mu)*rs*w[lane + 64*t];
        ushort h = f2b(y);
        Yh[(size_t)row*D_ + lane + 64*t] = h;
        Yl[(size_t)row*D_ + lane + 64*t] = f2b(y - b2f(h));
    }
}

// ------------- gather emb[q] + LayerNorm -> fp32 h -------------
__global__ __launch_bounds__(256)
void x_init(const int* __restrict__ qtok, const float* __restrict__ emb,
            const float* __restrict__ w, float* __restrict__ Y, int nrows)
{
    int row = blockIdx.x * 4 + (threadIdx.x >> 6);
    if (row >= nrows) return;
    int lane = threadIdx.x & 63;
    const float* x = emb + (size_t)qtok[row] * D_;
    float v[6]; float s = 0.f;
    #pragma unroll
    for (int t = 0; t < 6; ++t) { v[t] = x[lane + 64*t]; s += v[t]; }
    #pragma unroll
    for (int off = 32; off; off >>= 1) s += __shfl_xor(s, off);
    float mu = s * (1.f/(float)D_);
    float q = 0.f;
    #pragma unroll
    for (int t = 0; t < 6; ++t) { float d = v[t]-mu; q += d*d; }
    #pragma unroll
    for (int off = 32; off; off >>= 1) q += __shfl_xor(q, off);
    float rs = rsqrtf(q * (1.f/(float)D_) + 1e-5f);
    float* y = Y + (size_t)row * D_;
    #pragma unroll
    for (int t = 0; t < 6; ++t) y[lane + 64*t] = (v[t]-mu)*rs*w[lane + 64*t];
}

// ------------- weight split: fp32 -> bf16 hi/lo (per-layer 4 matrices) -------------
#define WE_SZ  (1632*384)   // 626688
#define P1_SZ  (384*768)    // 294912
#define WQ_SZ  (816*384)    // 313344
#define P2_SZ  (384*768)
#define WTOT   (WE_SZ + P1_SZ + WQ_SZ + P2_SZ)  // 1529856

__global__ __launch_bounds__(256)
void wconv(const float* __restrict__ we, const float* __restrict__ p1,
           const float* __restrict__ wq, const float* __restrict__ p2,
           ushort* __restrict__ wh, ushort* __restrict__ wl)
{
    int i = blockIdx.x*256 + threadIdx.x;
    if (i >= WTOT) return;
    float v;
    if (i < WE_SZ) v = we[i];
    else if (i < WE_SZ+P1_SZ) v = p1[i - WE_SZ];
    else if (i < WE_SZ+P1_SZ+WQ_SZ) v = wq[i - WE_SZ - P1_SZ];
    else v = p2[i - WE_SZ - P1_SZ - WQ_SZ];
    ushort h = f2b(v);
    wh[i] = h; wl[i] = f2b(v - b2f(h));
}

__global__ __launch_bounds__(256)
void wconv1(const float* __restrict__ src, int n,
            ushort* __restrict__ wh, ushort* __restrict__ wl)
{
    int i = blockIdx.x*256 + threadIdx.x;
    if (i >= n) return;
    float v = src[i];
    ushort h = f2b(v);
    wh[i] = h; wl[i] = f2b(v - b2f(h));
}

// ------------- MFMA split-bf16 GEMM: C[M,N] = [A1|A2] @ W^T (+C optional) -------------
__global__ __launch_bounds__(256)
void mm_bt(const ushort* __restrict__ A1h, const ushort* __restrict__ A1l, int lda1, int K1,
           const ushort* __restrict__ A2h, const ushort* __restrict__ A2l, int lda2,
           const ushort* __restrict__ Wgh, const ushort* __restrict__ Wgl,
           float* __restrict__ C, int ldc, int N, int K, int accum)
{
    __shared__ ushort Ah[64][32], Al[64][32], Wh[64][32], Wl[64][32];
    int tid = threadIdx.x;
    int row0 = blockIdx.y*64, col0 = blockIdx.x*64;
    int srow = tid >> 2, sseg = (tid & 3) * 8;
    int arow = row0 + srow;
    int wrow = col0 + srow;
    bool wok = wrow < N;
    int wid = tid >> 6, lane = tid & 63;
    int wr = wid >> 1, wc = wid & 1;
    int fr = lane & 15, fg = lane >> 4;
    f32x4 acc[2][2] = {};
    for (int k0 = 0; k0 < K; k0 += 32) {
        ushort8v va, vb, vc = {}, vd = {};
        if (k0 < K1) {
            va = *(const ushort8v*)(A1h + (size_t)arow*lda1 + k0 + sseg);
            vb = *(const ushort8v*)(A1l + (size_t)arow*lda1 + k0 + sseg);
        } else {
            va = *(const ushort8v*)(A2h + (size_t)arow*lda2 + (k0-K1) + sseg);
            vb = *(const ushort8v*)(A2l + (size_t)arow*lda2 + (k0-K1) + sseg);
        }
        if (wok) {
            vc = *(const ushort8v*)(Wgh + (size_t)wrow*K + k0 + sseg);
            vd = *(const ushort8v*)(Wgl + (size_t)wrow*K + k0 + sseg);
        }
        __syncthreads();
        *(ushort8v*)&Ah[srow][sseg] = va;
        *(ushort8v*)&Al[srow][sseg] = vb;
        *(ushort8v*)&Wh[srow][sseg] = vc;
        *(ushort8v*)&Wl[srow][sseg] = vd;
        __syncthreads();
        bf16x8 a_h[2], a_l[2], b_h[2], b_l[2];
        #pragma unroll
        for (int s = 0; s < 2; ++s) {
            a_h[s] = *(const bf16x8*)&Ah[wr*32 + s*16 + fr][fg*8];
            a_l[s] = *(const bf16x8*)&Al[wr*32 + s*16 + fr][fg*8];
            b_h[s] = *(const bf16x8*)&Wh[wc*32 + s*16 + fr][fg*8];
            b_l[s] = *(const bf16x8*)&Wl[wc*32 + s*16 + fr][fg*8];
        }
        #pragma unroll
        for (int s = 0; s < 2; ++s)
            #pragma unroll
            for (int u = 0; u < 2; ++u)
                acc[s][u] = __builtin_amdgcn_mfma_f32_16x16x32_bf16(a_h[s], b_h[u], acc[s][u], 0,0,0);
        #pragma unroll
        for (int s = 0; s < 2; ++s)
            #pragma unroll
            for (int u = 0; u < 2; ++u)
                acc[s][u] = __builtin_amdgcn_mfma_f32_16x16x32_bf16(a_h[s], b_l[u], acc[s][u], 0,0,0);
        #pragma unroll
        for (int s = 0; s < 2; ++s)
            #pragma unroll
            for (int u = 0; u < 2; ++u)
                acc[s][u] = __builtin_amdgcn_mfma_f32_16x16x32_bf16(a_l[s], b_h[u], acc[s][u], 0,0,0);
    }
    #pragma unroll
    for (int s = 0; s < 2; ++s) {
        int r = row0 + wr*32 + s*16 + fg*4;
        #pragma unroll
        for (int u = 0; u < 2; ++u) {
            int c = col0 + wc*32 + u*16 + fr;
            if (c < N) {
                #pragma unroll
                for (int j = 0; j < 4; ++j) {
                    size_t o = (size_t)(r+j)*ldc + c;
                    C[o] = accum ? (C[o] + acc[s][u][j]) : acc[s][u][j];
                }
            }
        }
    }
}

// ------------- MFMA split-bf16 GEGLU GEMM: Out = (A@W1^T) * gelu(A@W2^T), bf16 hi/lo out -------------
__global__ __launch_bounds__(256)
void mm_geglu(const ushort* __restrict__ Agh, const ushort* __restrict__ Agl, int lda,
              const ushort* __restrict__ W1h, const ushort* __restrict__ W1l,
              const ushort* __restrict__ W2h, const ushort* __restrict__ W2l,
              ushort* __restrict__ Oh, ushort* __restrict__ Ol, int ldo,
              int N, int K)
{
    __shared__ ushort Ah[64][32], Al[64][32];
    __shared__ ushort X1h[64][32], X1l[64][32], X2h[64][32], X2l[64][32];
    int tid = threadIdx.x;
    int row0 = blockIdx.y*64, col0 = blockIdx.x*64;
    int srow = tid >> 2, sseg = (tid & 3) * 8;
    int arow = row0 + srow;
    int wrow = col0 + srow;
    int wid = tid >> 6, lane = tid & 63;
    int wr = wid >> 1, wc = wid & 1;
    int fr = lane & 15, fg = lane >> 4;
    f32x4 acc1[2][2] = {}, acc2[2][2] = {};
    for (int k0 = 0; k0 < K; k0 += 32) {
        ushort8v va = *(const ushort8v*)(Agh + (size_t)arow*lda + k0 + sseg);
        ushort8v vb = *(const ushort8v*)(Agl + (size_t)arow*lda + k0 + sseg);
        ushort8v v1 = *(const ushort8v*)(W1h + (size_t)wrow*K + k0 + sseg);
        ushort8v v2 = *(const ushort8v*)(W1l + (size_t)wrow*K + k0 + sseg);
        ushort8v v3 = *(const ushort8v*)(W2h + (size_t)wrow*K + k0 + sseg);
        ushort8v v4 = *(const ushort8v*)(W2l + (size_t)wrow*K + k0 + sseg);
        __syncthreads();
        *(ushort8v*)&Ah[srow][sseg]  = va;
        *(ushort8v*)&Al[srow][sseg]  = vb;
        *(ushort8v*)&X1h[srow][sseg] = v1;
        *(ushort8v*)&X1l[srow][sseg] = v2;
        *(ushort8v*)&X2h[srow][sseg] = v3;
        *(ushort8v*)&X2l[srow][sseg] = v4;
        __syncthreads();
        bf16x8 a_h[2], a_l[2], b1h[2], b1l[2], b2h[2], b2l[2];
        #pragma unroll
        for (int s = 0; s < 2; ++s) {
            a_h[s] = *(const bf16x8*)&Ah[wr*32 + s*16 + fr][fg*8];
            a_l[s] = *(const bf16x8*)&Al[wr*32 + s*16 + fr][fg*8];
            b1h[s] = *(const bf16x8*)&X1h[wc*32 + s*16 + fr][fg*8];
            b1l[s] = *(const bf16x8*)&X1l[wc*32 + s*16 + fr][fg*8];
            b2h[s] = *(const bf16x8*)&X2h[wc*32 + s*16 + fr][fg*8];
            b2l[s] = *(const bf16x8*)&X2l[wc*32 + s*16 + fr][fg*8];
        }
        #pragma unroll
        for (int s = 0; s < 2; ++s)
            #pragma unroll
            for (int u = 0; u < 2; ++u) {
                acc1[s][u] = __builtin_amdgcn_mfma_f32_16x16x32_bf16(a_h[s], b1h[u], acc1[s][u], 0,0,0);
                acc2[s][u] = __builtin_amdgcn_mfma_f32_16x16x32_bf16(a_h[s], b2h[u], acc2[s][u], 0,0,0);
            }
        #pragma unroll
        for (int s = 0; s < 2; ++s)
            #pragma unroll
            for (int u = 0; u < 2; ++u) {
                acc1[s][u] = __builtin_amdgcn_mfma_f32_16x16x32_bf16(a_h[s], b1l[u], acc1[s][u], 0,0,0);
                acc2[s][u] = __builtin_amdgcn_mfma_f32_16x16x32_bf16(a_h[s], b2l[u], acc2[s][u], 0,0,0);
            }
        #pragma unroll
        for (int s = 0; s < 2; ++s)
            #pragma unroll
            for (int u = 0; u < 2; ++u) {
                acc1[s][u] = __builtin_amdgcn_mfma_f32_16x16x32_bf16(a_l[s], b1h[u], acc1[s][u], 0,0,0);
                acc2[s][u] = __builtin_amdgcn_mfma_f32_16x16x32_bf16(a_l[s], b2h[u], acc2[s][u], 0,0,0);
            }
    }
    #pragma unroll
    for (int s = 0; s < 2; ++s) {
        int r = row0 + wr*32 + s*16 + fg*4;
        #pragma unroll
        for (int u = 0; u < 2; ++u) {
            int c = col0 + wc*32 + u*16 + fr;
            #pragma unroll
            for (int j = 0; j < 4; ++j) {
                float g = acc1[s][u][j] * gelu_f(acc2[s][u][j]);
                ushort h = f2b(g);
                size_t o = (size_t)(r+j)*ldo + c;
                Oh[o] = h; Ol[o] = f2b(g - b2f(h));
            }
        }
    }
}

// ------------- MFMA batched PV: O[b](Mrows x 64-col tile) = P[b](Mrows x K) @ V[b](Kv x N) -------------
// P bf16 [Mrows][ldp], zero in cols >= Kv. V bf16 [Kv][ldv]. Output bf16 hi/lo.
// V transposed into LDS with k-group XOR swizzle for aligned b128 fragment reads.
__global__ __launch_bounds__(256)
void pv_mfma(const ushort* __restrict__ P, int ldp, long sP,
             const ushort* __restrict__ V, int ldv, long sV,
             ushort* __restrict__ Oh, ushort* __restrict__ Ol, int ldo, long sO,
             int Mrows, int K, int Kv)
{
    __shared__ ushort Ps[64*32];
    __shared__ ushort Vs[64*32];
    const ushort* Pb = P + (size_t)blockIdx.z * sP;
    const ushort* Vb = V + (size_t)blockIdx.z * sV;
    ushort* Ohb = Oh + (size_t)blockIdx.z * sO;
    ushort* Olb = Ol + (size_t)blockIdx.z * sO;
    int tid = threadIdx.x;
    int row0 = blockIdx.y*64, col0 = blockIdx.x*64;
    int wid = tid >> 6, lane = tid & 63;
    int wr = wid >> 1, wc = wid & 1;
    int fr = lane & 15, fg = lane >> 4;
    int prow = tid >> 2, pseg = (tid & 3) * 8;
    int vk = tid & 31, vc8 = (tid >> 5) * 8;
    f32x4 acc[2][2] = {};
    for (int k0 = 0; k0 < K; k0 += 32) {
        ushort8v pv_ = {};
        int grow = row0 + prow;
        if (grow < Mrows)
            pv_ = *(const ushort8v*)(Pb + (size_t)grow*ldp + k0 + pseg);
        ushort8v vv = {};
        int gk = k0 + vk;
        if (gk < Kv)
            vv = *(const ushort8v*)(Vb + (size_t)gk*ldv + col0 + vc8);
        __syncthreads();
        *(ushort8v*)&Ps[prow*32 + pseg] = pv_;
        #pragma unroll
        for (int i = 0; i < 8; ++i) {
            int c = vc8 + i;
            Vs[c*32 + (vk & 7) + 8*((vk >> 3) ^ ((c >> 3) & 3))] = vv[i];
        }
        __syncthreads();
        bf16x8 a[2], b[2];
        #pragma unroll
        for (int s = 0; s < 2; ++s)
            a[s] = *(const bf16x8*)&Ps[(wr*32 + s*16 + fr)*32 + fg*8];
        #pragma unroll
        for (int u = 0; u < 2; ++u) {
            int c = wc*32 + u*16 + fr;
            b[u] = *(const bf16x8*)&Vs[c*32 + 8*(fg ^ ((c >> 3) & 3))];
        }
        #pragma unroll
        for (int s = 0; s < 2; ++s)
            #pragma unroll
            for (int u = 0; u < 2; ++u)
                acc[s][u] = __builtin_amdgcn_mfma_f32_16x16x32_bf16(a[s], b[u], acc[s][u], 0,0,0);
    }
    #pragma unroll
    for (int s = 0; s < 2; ++s) {
        int rbase = row0 + wr*32 + s*16 + fg*4;
        #pragma unroll
        for (int u = 0; u < 2; ++u) {
            int c = col0 + wc*32 + u*16 + fr;
            #pragma unroll
            for (int j = 0; j < 4; ++j) {
                int r = rbase + j;
                if (r < Mrows) {
                    float x = acc[s][u][j];
                    ushort h = f2b(x);
                    size_t o = (size_t)r*ldo + c;
                    Ohb[o] = h; Olb[o] = f2b(x - b2f(h));
                }
            }
        }
    }
}

// ------------- attention 1 scores -> normalized P (bf16) -------------
__global__ __launch_bounds__(256)
void attn1_score(const float* __restrict__ qk, const float* __restrict__ bm, int blk,
                 ushort* __restrict__ P)
{
    __shared__ float qrs[50][QK_];
    __shared__ float krs[S_][QK_+1];
    int b = blockIdx.x, r0 = blockIdx.y*50;
    int tid = threadIdx.x;
    for (int idx = tid; idx < 50*QK_; idx += 256) {
        int r = idx / QK_, c = idx % QK_;
        qrs[r][c] = qk[((size_t)(b*S_ + r0 + r))*96 + c];
    }
    for (int idx = tid; idx < S_*QK_; idx += 256) {
        int r = idx / QK_, c = idx % QK_;
        krs[r][c] = qk[((size_t)(b*S_ + r))*96 + 48 + c];
    }
    __syncthreads();
    float bmv = bm[blk];
    float sp = (bmv > 20.f) ? bmv : log1pf(expf(bmv));
    const float scale = 0.14433756729740643f;
    int w = tid >> 6, lane = tid & 63;
    for (int t = 0; t < 13; ++t) {
        int li = w + 4*t;
        if (li >= 50) break;
        int i = r0 + li;
        int j1 = lane, j2 = lane + 64;
        float s1 = -1e30f, s2 = -1e30f;
        if (j1 <= i) {
            float acc = 0.f;
            #pragma unroll
            for (int l = 0; l < QK_; ++l) acc += qrs[li][l]*krs[j1][l];
            s1 = acc*scale + sp*(float)(j1 - i);
        }
        if (j2 <= i) {
            float acc = 0.f;
            #pragma unroll
            for (int l = 0; l < QK_; ++l) acc += qrs[li][l]*krs[j2][l];
            s2 = acc*scale + sp*(float)(j2 - i);
        }
        float m = fmaxf(s1, s2);
        #pragma unroll
        for (int off = 32; off; off >>= 1) m = fmaxf(m, __shfl_xor(m, off));
        float p1 = (j1 <= i) ? expf(s1 - m) : 0.f;
        float p2 = (j2 <= i) ? expf(s2 - m) : 0.f;
        float sum = p1 + p2;
        #pragma unroll
        for (int off = 32; off; off >>= 1) sum += __shfl_xor(sum, off);
        float inv = 1.f / sum;
        ushort* prow = P + ((size_t)(b*S_) + i)*128;
        prow[j1] = f2b(p1*inv);
        prow[j2] = f2b(p2*inv);
    }
}

// ------------- attention 2 scores -> normalized P (bf16) -------------
__global__ __launch_bounds__(256)
void attn2_score(const float* __restrict__ q2, const float* __restrict__ k2,
                 ushort* __restrict__ P)
{
    __shared__ float ks[NPTS_][QK_+1];
    int b = blockIdx.x, r0 = blockIdx.y*20;
    int tid = threadIdx.x;
    for (int idx = tid; idx < NPTS_*QK_; idx += 256) {
        int r = idx / QK_, c = idx % QK_;
        ks[r][c] = k2[((size_t)(b*NPTS_ + r))*QK_ + c];
    }
    __syncthreads();
    const float scale = 0.14433756729740643f;
    int w = tid >> 6, lane = tid & 63;
    for (int t = 0; t < 5; ++t) {
        int i = r0 + w + 4*t;
        const float* qr = q2 + ((size_t)(b*S_ + i))*QK_;
        float s[4] = {0.f,0.f,0.f,0.f};
        for (int l = 0; l < QK_; ++l) {
            float ql = qr[l];
            #pragma unroll
            for (int r = 0; r < 4; ++r) s[r] += ql * ks[lane + 64*r][l];
        }
        #pragma unroll
        for (int r = 0; r < 4; ++r) s[r] *= scale;
        float m = fmaxf(fmaxf(s[0],s[1]), fmaxf(s[2],s[3]));
        #pragma unroll
        for (int off = 32; off; off >>= 1) m = fmaxf(m, __shfl_xor(m, off));
        float p[4]; float sum = 0.f;
        #pragma unroll
        for (int r = 0; r < 4; ++r) { p[r] = expf(s[r]-m); sum += p[r]; }
        #pragma unroll
        for (int off = 32; off; off >>= 1) sum += __shfl_xor(sum, off);
        float inv = 1.f / sum;
        ushort* prow = P + ((size_t)(b*S_) + i)*256;
        #pragma unroll
        for (int r = 0; r < 4; ++r) prow[lane + 64*r] = f2b(p[r]*inv);
    }
}

// ------------- P1/P2 = pt_emb @ Wkv halves (fp32) -------------
__global__ __launch_bounds__(256)
void pk_proj(const float* __restrict__ pt_emb, const float* __restrict__ Wkv,
             float* __restrict__ P12)
{
    int e = blockIdx.x*256 + threadIdx.x;
    if (e >= 2*NTOK_*816) return;
    int half = e / (NTOK_*816);
    int rem  = e % (NTOK_*816);
    int t = rem / 816, c = rem % 816;
    const float* x = pt_emb + (size_t)t*192;
    const float* wv = Wkv + (size_t)c*384 + half*192;
    float s = 0.f;
    for (int k = 0; k < 192; ++k) s += x[k]*wv[k];
    P12[e] = s;
}

// ------------- gather pk rows -> k2 (fp32), geglu'd values gv (bf16) -------------
__global__ __launch_bounds__(256)
void pk_gather(const int* __restrict__ pts, const float* __restrict__ P12,
               float* __restrict__ k2, ushort* __restrict__ gv)
{
    int pair = blockIdx.x*4 + (threadIdx.x >> 6);
    int lane = threadIdx.x & 63;
    const float* P1 = P12;
    const float* P2 = P12 + NTOK_*816;
    int t0 = pts[2*pair], t1 = pts[2*pair+1];
    const float* a = P1 + (size_t)t0*816;
    const float* c = P2 + (size_t)t1*816;
    if (lane < QK_) k2[(size_t)pair*QK_ + lane] = a[lane] + c[lane];
    #pragma unroll
    for (int t = 0; t < 6; ++t) {
        int i = lane + 64*t;
        float lin = a[48 + i] + c[48 + i];
        float pre = a[432 + i] + c[432 + i];
        gv[(size_t)pair*D_ + i] = f2b(lin * gelu_f(pre));
    }
}

extern "C" void kernel_launch(void* const* d_in, const int* in_sizes, int n_in,
                              void* d_out, int out_size, void* d_ws, size_t ws_size,
                              hipStream_t stream)
{
    const int*   qtok  = (const int*)d_in[0];
    const int*   pts   = (const int*)d_in[1];
    const float* emb   = (const float*)d_in[2];
    const float* ptemb = (const float*)d_in[3];
    const float* normw = (const float*)d_in[4];
    const float* outw  = (const float*)d_in[5];
    const float* ln1   = (const float*)d_in[6];
    const float* expand= (const float*)d_in[7];
    const float* proj1 = (const float*)d_in[8];
    const float* bm    = (const float*)d_in[9];
    const float* ln2   = (const float*)d_in[10];
    const float* Wq    = (const float*)d_in[11];
    const float* Wkv   = (const float*)d_in[12];
    const float* proj2 = (const float*)d_in[13];
    float* out = (float*)d_out;

    char* base = (char*)d_ws;
    size_t off = 0;
    auto alloc = [&](size_t bytes){ void* p = base + off; off += (bytes + 255) & ~(size_t)255; return p; };
    float*  h     = (float*) alloc((size_t)M_*D_*4);
    ushort* nhi   = (ushort*)alloc((size_t)M_*D_*2);
    ushort* nlo   = (ushort*)alloc((size_t)M_*D_*2);
    float*  qk1   = (float*) alloc((size_t)M_*96*4);     // qr2 aliases
    ushort* geglh = (ushort*)alloc((size_t)M_*E_*2);     // gloc_h aliases
    ushort* gegll = (ushort*)alloc((size_t)M_*E_*2);     // gloc_l aliases
    ushort* atbh  = (ushort*)alloc((size_t)M_*D_*2);
    ushort* atbl  = (ushort*)alloc((size_t)M_*D_*2);
    ushort* Pbuf  = (ushort*)alloc((size_t)M_*256*2);
    ushort* gv    = (ushort*)alloc((size_t)B_*NPTS_*D_*2);
    float*  P12   = (float*) alloc((size_t)2*NTOK_*816*4);
    float*  k2    = (float*) alloc((size_t)B_*NPTS_*QK_*4);
    ushort* wbh   = (ushort*)alloc((size_t)WTOT*2);
    ushort* wbl   = (ushort*)alloc((size_t)WTOT*2);

    float*  qr2   = qk1;
    ushort* gloch = geglh;
    ushort* glocl = gegll;

    const size_t oWE = 0;
    const size_t oP1 = WE_SZ;
    const size_t oWQ = WE_SZ + P1_SZ;
    const size_t oP2 = WE_SZ + P1_SZ + WQ_SZ;

    x_init<<<M_/4, 256, 0, stream>>>(qtok, emb, normw, h, M_);

    for (int blk = 0; blk < NB_; ++blk) {
        wconv<<<(WTOT+255)/256, 256, 0, stream>>>(
            expand + (size_t)blk*WE_SZ, proj1 + (size_t)blk*P1_SZ,
            Wq + (size_t)blk*WQ_SZ, proj2 + (size_t)blk*P2_SZ, wbh, wbl);

        ln_rows<<<M_/4, 256, 0, stream>>>(h, ln1 + blk*D_, nhi, nlo, M_);
        // qk : N=96, K=384
        mm_bt<<<dim3(2, M_/64), 256, 0, stream>>>(nhi, nlo, D_, D_, nhi, nlo, D_,
            wbh + oWE, wbl + oWE, qk1, 96, 96, D_, 0);
        // geglu768
        mm_geglu<<<dim3(12, M_/64), 256, 0, stream>>>(nhi, nlo, D_,
            wbh + oWE + (size_t)96*D_,  wbl + oWE + (size_t)96*D_,
            wbh + oWE + (size_t)864*D_, wbl + oWE + (size_t)864*D_,
            geglh, gegll, E_, E_, D_);
        attn1_score<<<dim3(B_,2), 256, 0, stream>>>(qk1, bm, blk, Pbuf);
        pv_mfma<<<dim3(6,2,B_), 256, 0, stream>>>(Pbuf, 128, (long)S_*128,
            geglh + LOCAL_, E_, (long)S_*E_,
            atbh, atbl, D_, (long)S_*D_, S_, 128, S_);
        // h += [geglu_local | attn] @ W_p1^T
        mm_bt<<<dim3(6, M_/64), 256, 0, stream>>>(geglh, gegll, E_, D_, atbh, atbl, D_,
            wbh + oP1, wbl + oP1, h, D_, D_, E_, 1);

        ln_rows<<<M_/4, 256, 0, stream>>>(h, ln2 + blk*D_, nhi, nlo, M_);
        // qr2 : N=48
        mm_bt<<<dim3(1, M_/64), 256, 0, stream>>>(nhi, nlo, D_, D_, nhi, nlo, D_,
            wbh + oWQ, wbl + oWQ, qr2, QK_, QK_, D_, 0);
        // g_local geglu384
        mm_geglu<<<dim3(6, M_/64), 256, 0, stream>>>(nhi, nlo, D_,
            wbh + oWQ + (size_t)48*D_,  wbl + oWQ + (size_t)48*D_,
            wbh + oWQ + (size_t)432*D_, wbl + oWQ + (size_t)432*D_,
            gloch, glocl, D_, D_, D_);
        // pk path
        pk_proj<<<(2*NTOK_*816 + 255)/256, 256, 0, stream>>>(ptemb,
            Wkv + (size_t)blk*816*D_, P12);
        pk_gather<<<B_*NPTS_/4, 256, 0, stream>>>(pts, P12, k2, gv);
        attn2_score<<<dim3(B_,5), 256, 0, stream>>>(qr2, k2, Pbuf);
        pv_mfma<<<dim3(6,2,B_), 256, 0, stream>>>(Pbuf, 256, (long)S_*256,
            gv, D_, (long)NPTS_*D_,
            atbh, atbl, D_, (long)S_*D_, S_, 256, 256);
        // h += [g_local | attn2] @ W_p2^T
        mm_bt<<<dim3(6, M_/64), 256, 0, stream>>>(gloch, glocl, D_, D_, atbh, atbl, D_,
            wbh + oP2, wbl + oP2, h, D_, D_, E_, 1);
    }

    ln_rows<<<M_/4, 256, 0, stream>>>(h, normw, nhi, nlo, M_);
    wconv1<<<(NTOK_*D_ + 255)/256, 256, 0, stream>>>(outw, NTOK_*D_, wbh, wbl);
    mm_bt<<<dim3(2, M_/64), 256, 0, stream>>>(nhi, nlo, D_, D_, nhi, nlo, D_,
        wbh, wbl, out, NTOK_, NTOK_, D_, 0);
}

// Round 5
// 3028.449 us; speedup vs baseline: 4.0444x; 1.0117x over previous
//
#include <hip/hip_runtime.h>
#include <hip/hip_bf16.h>
#include <math.h>

#define B_    128
#define S_    100
#define D_    384
#define QK_   48
#define E_    768
#define LOCAL_ 384
#define NB_   8
#define NTOK_ 100
#define NPTS_ 256
#define M_    (B_*S_)   // 12800

typedef unsigned short ushort;
typedef __attribute__((ext_vector_type(8))) short  bf16x8;
typedef __attribute__((ext_vector_type(8))) unsigned short ushort8v;
typedef __attribute__((ext_vector_type(4))) float  f32x4;

static __device__ __forceinline__ float gelu_f(float x) {
    return 0.5f * x * (1.0f + erff(x * 0.70710678118654752440f));
}
// fp32 -> bf16 (round-to-nearest-even), bit-level
static __device__ __forceinline__ ushort f2b(float f) {
    union { float f; unsigned u; } x; x.f = f;
    unsigned r = x.u + 0x7FFFu + ((x.u >> 16) & 1u);
    return (ushort)(r >> 16);
}
static __device__ __forceinline__ float b2f(ushort u) {
    union { unsigned u; float f; } x; x.u = ((unsigned)u) << 16;
    return x.f;
}

// ---------------- LayerNorm: fp32 in -> bf16 hi/lo out ----------------
__global__ __launch_bounds__(256)
void ln_rows(const float* __restrict__ X, const float* __restrict__ w,
             ushort* __restrict__ Yh, ushort* __restrict__ Yl, int nrows)
{
    int row = blockIdx.x * 4 + (threadIdx.x >> 6);
    if (row >= nrows) return;
    int lane = threadIdx.x & 63;
    const float* x = X + (size_t)row * D_;
    float v[6]; float s = 0.f;
    #pragma unroll
    for (int t = 0; t < 6; ++t) { v[t] = x[lane + 64*t]; s += v[t]; }
    #pragma unroll
    for (int off = 32; off; off >>= 1) s += __shfl_xor(s, off);
    float mu = s * (1.f/(float)D_);
    float q = 0.f;
    #pragma unroll
    for (int t = 0; t < 6; ++t) { float d = v[t]-mu; q += d*d; }
    #pragma unroll
    for (int off = 32; off; off >>= 1) q += __shfl_xor(q, off);
    float rs = rsqrtf(q * (1.f/(float)D_) + 1e-5f);
    #pragma unroll
    for (int t = 0; t < 6; ++t) {
        float y = (v[t]-mu)*rs*w[lane + 64*t];
        ushort h = f2b(y);
        Yh[(size_t)row*D_ + lane + 64*t] = h;
        Yl[(size_t)row*D_ + lane + 64*t] = f2b(y - b2f(h));
    }
}

// ------------- gather emb[q] + LayerNorm -> fp32 h -------------
__global__ __launch_bounds__(256)
void x_init(const int* __restrict__ qtok, const float* __restrict__ emb,
            const float* __restrict__ w, float* __restrict__ Y, int nrows)
{
    int row = blockIdx.x * 4 + (threadIdx.x >> 6);
    if (row >= nrows) return;
    int lane = threadIdx.x & 63;
    const float* x = emb + (size_t)qtok[row] * D_;
    float v[6]; float s = 0.f;
    #pragma unroll
    for (int t = 0; t < 6; ++t) { v[t] = x[lane + 64*t]; s += v[t]; }
    #pragma unroll
    for (int off = 32; off; off >>= 1) s += __shfl_xor(s, off);
    float mu = s * (1.f/(float)D_);
    float q = 0.f;
    #pragma unroll
    for (int t = 0; t < 6; ++t) { float d = v[t]-mu; q += d*d; }
    #pragma unroll
    for (int off = 32; off; off >>= 1) q += __shfl_xor(q, off);
    float rs = rsqrtf(q * (1.f/(float)D_) + 1e-5f);
    float* y = Y + (size_t)row * D_;
    #pragma unroll
    for (int t = 0; t < 6; ++t) y[lane + 64*t] = (v[t]-mu)*rs*w[lane + 64*t];
}

// ------------- weight split: fp32 -> bf16 hi/lo (per-layer 4 matrices) -------------
#define WE_SZ  (1632*384)
#define P1_SZ  (384*768)
#define WQ_SZ  (816*384)
#define P2_SZ  (384*768)
#define WTOT   (WE_SZ + P1_SZ + WQ_SZ + P2_SZ)

__global__ __launch_bounds__(256)
void wconv(const float* __restrict__ we, const float* __restrict__ p1,
           const float* __restrict__ wq, const float* __restrict__ p2,
           ushort* __restrict__ wh, ushort* __restrict__ wl)
{
    int i = blockIdx.x*256 + threadIdx.x;
    if (i >= WTOT) return;
    float v;
    if (i < WE_SZ) v = we[i];
    else if (i < WE_SZ+P1_SZ) v = p1[i - WE_SZ];
    else if (i < WE_SZ+P1_SZ+WQ_SZ) v = wq[i - WE_SZ - P1_SZ];
    else v = p2[i - WE_SZ - P1_SZ - WQ_SZ];
    ushort h = f2b(v);
    wh[i] = h; wl[i] = f2b(v - b2f(h));
}

__global__ __launch_bounds__(256)
void wconv1(const float* __restrict__ src, int n,
            ushort* __restrict__ wh, ushort* __restrict__ wl)
{
    int i = blockIdx.x*256 + threadIdx.x;
    if (i >= n) return;
    float v = src[i];
    ushort h = f2b(v);
    wh[i] = h; wl[i] = f2b(v - b2f(h));
}

// ------------- MFMA split-bf16 GEMM: C[M,N] = [A1|A2] @ W^T (+C optional) -------------
// BK=64, padded LDS stride 72 (rows step 4 banks -> 2-way conflict = free).
// K and K1 must be multiples of 64.
__global__ __launch_bounds__(256)
void mm_bt(const ushort* __restrict__ A1h, const ushort* __restrict__ A1l, int lda1, int K1,
           const ushort* __restrict__ A2h, const ushort* __restrict__ A2l, int lda2,
           const ushort* __restrict__ Wgh, const ushort* __restrict__ Wgl,
           float* __restrict__ C, int ldc, int N, int K, int accum)
{
    __shared__ ushort Ah[64][72], Al[64][72], Wh[64][72], Wl[64][72];
    int tid = threadIdx.x;
    int row0 = blockIdx.y*64, col0 = blockIdx.x*64;
    int srow = tid >> 3;        // 0..31
    int sseg = (tid & 7) * 8;   // 0,8,..,56
    int wid = tid >> 6, lane = tid & 63;
    int wr = wid >> 1, wc = wid & 1;
    int fr = lane & 15, fg = lane >> 4;
    f32x4 acc[2][2] = {};
    for (int k0 = 0; k0 < K; k0 += 64) {
        ushort8v va[2], vb[2], vc[2], vd[2];
        #pragma unroll
        for (int p = 0; p < 2; ++p) {
            int r = p*32 + srow;
            int arow = row0 + r;
            int wrow = col0 + r;
            int gk = k0 + sseg;
            if (gk < K1) {
                va[p] = *(const ushort8v*)(A1h + (size_t)arow*lda1 + gk);
                vb[p] = *(const ushort8v*)(A1l + (size_t)arow*lda1 + gk);
            } else {
                va[p] = *(const ushort8v*)(A2h + (size_t)arow*lda2 + (gk-K1));
                vb[p] = *(const ushort8v*)(A2l + (size_t)arow*lda2 + (gk-K1));
            }
            if (wrow < N) {
                vc[p] = *(const ushort8v*)(Wgh + (size_t)wrow*K + gk);
                vd[p] = *(const ushort8v*)(Wgl + (size_t)wrow*K + gk);
            } else {
                vc[p] = (ushort8v){0,0,0,0,0,0,0,0};
                vd[p] = (ushort8v){0,0,0,0,0,0,0,0};
            }
        }
        __syncthreads();
        #pragma unroll
        for (int p = 0; p < 2; ++p) {
            int r = p*32 + srow;
            *(ushort8v*)&Ah[r][sseg] = va[p];
            *(ushort8v*)&Al[r][sseg] = vb[p];
            *(ushort8v*)&Wh[r][sseg] = vc[p];
            *(ushort8v*)&Wl[r][sseg] = vd[p];
        }
        __syncthreads();
        #pragma unroll
        for (int kk = 0; kk < 64; kk += 32) {
            bf16x8 a_h[2], a_l[2], b_h[2], b_l[2];
            #pragma unroll
            for (int s = 0; s < 2; ++s) {
                a_h[s] = *(const bf16x8*)&Ah[wr*32 + s*16 + fr][kk + fg*8];
                a_l[s] = *(const bf16x8*)&Al[wr*32 + s*16 + fr][kk + fg*8];
                b_h[s] = *(const bf16x8*)&Wh[wc*32 + s*16 + fr][kk + fg*8];
                b_l[s] = *(const bf16x8*)&Wl[wc*32 + s*16 + fr][kk + fg*8];
            }
            #pragma unroll
            for (int s = 0; s < 2; ++s)
                #pragma unroll
                for (int u = 0; u < 2; ++u)
                    acc[s][u] = __builtin_amdgcn_mfma_f32_16x16x32_bf16(a_h[s], b_h[u], acc[s][u], 0,0,0);
            #pragma unroll
            for (int s = 0; s < 2; ++s)
                #pragma unroll
                for (int u = 0; u < 2; ++u)
                    acc[s][u] = __builtin_amdgcn_mfma_f32_16x16x32_bf16(a_h[s], b_l[u], acc[s][u], 0,0,0);
            #pragma unroll
            for (int s = 0; s < 2; ++s)
                #pragma unroll
                for (int u = 0; u < 2; ++u)
                    acc[s][u] = __builtin_amdgcn_mfma_f32_16x16x32_bf16(a_l[s], b_h[u], acc[s][u], 0,0,0);
        }
        __syncthreads();
    }
    #pragma unroll
    for (int s = 0; s < 2; ++s) {
        int r = row0 + wr*32 + s*16 + fg*4;
        #pragma unroll
        for (int u = 0; u < 2; ++u) {
            int c = col0 + wc*32 + u*16 + fr;
            if (c < N) {
                #pragma unroll
                for (int j = 0; j < 4; ++j) {
                    size_t o = (size_t)(r+j)*ldc + c;
                    C[o] = accum ? (C[o] + acc[s][u][j]) : acc[s][u][j];
                }
            }
        }
    }
}

// ------------- MFMA split-bf16 GEGLU GEMM: Out = (A@W1^T) * gelu(A@W2^T), bf16 hi/lo out -------------
// BK=32, padded LDS stride 40 (rows step 20 banks, 8-cycle -> 2-way = free).
__global__ __launch_bounds__(256)
void mm_geglu(const ushort* __restrict__ Agh, const ushort* __restrict__ Agl, int lda,
              const ushort* __restrict__ W1h, const ushort* __restrict__ W1l,
              const ushort* __restrict__ W2h, const ushort* __restrict__ W2l,
              ushort* __restrict__ Oh, ushort* __restrict__ Ol, int ldo,
              int N, int K)
{
    __shared__ ushort Ah[64][40], Al[64][40];
    __shared__ ushort X1h[64][40], X1l[64][40], X2h[64][40], X2l[64][40];
    int tid = threadIdx.x;
    int row0 = blockIdx.y*64, col0 = blockIdx.x*64;
    int srow = tid >> 2, sseg = (tid & 3) * 8;
    int arow = row0 + srow;
    int wrow = col0 + srow;
    int wid = tid >> 6, lane = tid & 63;
    int wr = wid >> 1, wc = wid & 1;
    int fr = lane & 15, fg = lane >> 4;
    f32x4 acc1[2][2] = {}, acc2[2][2] = {};
    for (int k0 = 0; k0 < K; k0 += 32) {
        ushort8v va = *(const ushort8v*)(Agh + (size_t)arow*lda + k0 + sseg);
        ushort8v vb = *(const ushort8v*)(Agl + (size_t)arow*lda + k0 + sseg);
        ushort8v v1 = *(const ushort8v*)(W1h + (size_t)wrow*K + k0 + sseg);
        ushort8v v2 = *(const ushort8v*)(W1l + (size_t)wrow*K + k0 + sseg);
        ushort8v v3 = *(const ushort8v*)(W2h + (size_t)wrow*K + k0 + sseg);
        ushort8v v4 = *(const ushort8v*)(W2l + (size_t)wrow*K + k0 + sseg);
        __syncthreads();
        *(ushort8v*)&Ah[srow][sseg]  = va;
        *(ushort8v*)&Al[srow][sseg]  = vb;
        *(ushort8v*)&X1h[srow][sseg] = v1;
        *(ushort8v*)&X1l[srow][sseg] = v2;
        *(ushort8v*)&X2h[srow][sseg] = v3;
        *(ushort8v*)&X2l[srow][sseg] = v4;
        __syncthreads();
        bf16x8 a_h[2], a_l[2], b1h[2], b1l[2], b2h[2], b2l[2];
        #pragma unroll
        for (int s = 0; s < 2; ++s) {
            a_h[s] = *(const bf16x8*)&Ah[wr*32 + s*16 + fr][fg*8];
            a_l[s] = *(const bf16x8*)&Al[wr*32 + s*16 + fr][fg*8];
            b1h[s] = *(const bf16x8*)&X1h[wc*32 + s*16 + fr][fg*8];
            b1l[s] = *(const bf16x8*)&X1l[wc*32 + s*16 + fr][fg*8];
            b2h[s] = *(const bf16x8*)&X2h[wc*32 + s*16 + fr][fg*8];
            b2l[s] = *(const bf16x8*)&X2l[wc*32 + s*16 + fr][fg*8];
        }
        #pragma unroll
        for (int s = 0; s < 2; ++s)
            #pragma unroll
            for (int u = 0; u < 2; ++u) {
                acc1[s][u] = __builtin_amdgcn_mfma_f32_16x16x32_bf16(a_h[s], b1h[u], acc1[s][u], 0,0,0);
                acc2[s][u] = __builtin_amdgcn_mfma_f32_16x16x32_bf16(a_h[s], b2h[u], acc2[s][u], 0,0,0);
            }
        #pragma unroll
        for (int s = 0; s < 2; ++s)
            #pragma unroll
            for (int u = 0; u < 2; ++u) {
                acc1[s][u] = __builtin_amdgcn_mfma_f32_16x16x32_bf16(a_h[s], b1l[u], acc1[s][u], 0,0,0);
                acc2[s][u] = __builtin_amdgcn_mfma_f32_16x16x32_bf16(a_h[s], b2l[u], acc2[s][u], 0,0,0);
            }
        #pragma unroll
        for (int s = 0; s < 2; ++s)
            #pragma unroll
            for (int u = 0; u < 2; ++u) {
                acc1[s][u] = __builtin_amdgcn_mfma_f32_16x16x32_bf16(a_l[s], b1h[u], acc1[s][u], 0,0,0);
                acc2[s][u] = __builtin_amdgcn_mfma_f32_16x16x32_bf16(a_l[s], b2h[u], acc2[s][u], 0,0,0);
            }
    }
    #pragma unroll
    for (int s = 0; s < 2; ++s) {
        int r = row0 + wr*32 + s*16 + fg*4;
        #pragma unroll
        for (int u = 0; u < 2; ++u) {
            int c = col0 + wc*32 + u*16 + fr;
            #pragma unroll
            for (int j = 0; j < 4; ++j) {
                float g = acc1[s][u][j] * gelu_f(acc2[s][u][j]);
                ushort h = f2b(g);
                size_t o = (size_t)(r+j)*ldo + c;
                Oh[o] = h; Ol[o] = f2b(g - b2f(h));
            }
        }
    }
}

// ------------- MFMA batched PV -------------
__global__ __launch_bounds__(256)
void pv_mfma(const ushort* __restrict__ P, int ldp, long sP,
             const ushort* __restrict__ V, int ldv, long sV,
             ushort* __restrict__ Oh, ushort* __restrict__ Ol, int ldo, long sO,
             int Mrows, int K, int Kv)
{
    __shared__ ushort Ps[64][40];
    __shared__ ushort Vs[64*32];
    const ushort* Pb = P + (size_t)blockIdx.z * sP;
    const ushort* Vb = V + (size_t)blockIdx.z * sV;
    ushort* Ohb = Oh + (size_t)blockIdx.z * sO;
    ushort* Olb = Ol + (size_t)blockIdx.z * sO;
    int tid = threadIdx.x;
    int row0 = blockIdx.y*64, col0 = blockIdx.x*64;
    int wid = tid >> 6, lane = tid & 63;
    int wr = wid >> 1, wc = wid & 1;
    int fr = lane & 15, fg = lane >> 4;
    int prow = tid >> 2, pseg = (tid & 3) * 8;
    int vk = tid & 31, vc8 = (tid >> 5) * 8;
    f32x4 acc[2][2] = {};
    for (int k0 = 0; k0 < K; k0 += 32) {
        ushort8v pv_ = {};
        int grow = row0 + prow;
        if (grow < Mrows)
            pv_ = *(const ushort8v*)(Pb + (size_t)grow*ldp + k0 + pseg);
        ushort8v vv = {};
        int gk = k0 + vk;
        if (gk < Kv)
            vv = *(const ushort8v*)(Vb + (size_t)gk*ldv + col0 + vc8);
        __syncthreads();
        *(ushort8v*)&Ps[prow][pseg] = pv_;
        #pragma unroll
        for (int i = 0; i < 8; ++i) {
            int c = vc8 + i;
            Vs[c*32 + (vk & 7) + 8*((vk >> 3) ^ ((c >> 3) & 3))] = vv[i];
        }
        __syncthreads();
        bf16x8 a[2], b[2];
        #pragma unroll
        for (int s = 0; s < 2; ++s)
            a[s] = *(const bf16x8*)&Ps[wr*32 + s*16 + fr][fg*8];
        #pragma unroll
        for (int u = 0; u < 2; ++u) {
            int c = wc*32 + u*16 + fr;
            b[u] = *(const bf16x8*)&Vs[c*32 + 8*(fg ^ ((c >> 3) & 3))];
        }
        #pragma unroll
        for (int s = 0; s < 2; ++s)
            #pragma unroll
            for (int u = 0; u < 2; ++u)
                acc[s][u] = __builtin_amdgcn_mfma_f32_16x16x32_bf16(a[s], b[u], acc[s][u], 0,0,0);
    }
    #pragma unroll
    for (int s = 0; s < 2; ++s) {
        int rbase = row0 + wr*32 + s*16 + fg*4;
        #pragma unroll
        for (int u = 0; u < 2; ++u) {
            int c = col0 + wc*32 + u*16 + fr;
            #pragma unroll
            for (int j = 0; j < 4; ++j) {
                int r = rbase + j;
                if (r < Mrows) {
                    float x = acc[s][u][j];
                    ushort h = f2b(x);
                    size_t o = (size_t)r*ldo + c;
                    Ohb[o] = h; Olb[o] = f2b(x - b2f(h));
                }
            }
        }
    }
}

// ------------- attention 1 scores -> normalized P (bf16) -------------
__global__ __launch_bounds__(256)
void attn1_score(const float* __restrict__ qk, const float* __restrict__ bm, int blk,
                 ushort* __restrict__ P)
{
    __shared__ float qrs[50][QK_];
    __shared__ float krs[S_][QK_+1];
    int b = blockIdx.x, r0 = blockIdx.y*50;
    int tid = threadIdx.x;
    for (int idx = tid; idx < 50*QK_; idx += 256) {
        int r = idx / QK_, c = idx % QK_;
        qrs[r][c] = qk[((size_t)(b*S_ + r0 + r))*96 + c];
    }
    for (int idx = tid; idx < S_*QK_; idx += 256) {
        int r = idx / QK_, c = idx % QK_;
        krs[r][c] = qk[((size_t)(b*S_ + r))*96 + 48 + c];
    }
    __syncthreads();
    float bmv = bm[blk];
    float sp = (bmv > 20.f) ? bmv : log1pf(expf(bmv));
    const float scale = 0.14433756729740643f;
    int w = tid >> 6, lane = tid & 63;
    for (int t = 0; t < 13; ++t) {
        int li = w + 4*t;
        if (li >= 50) break;
        int i = r0 + li;
        int j1 = lane, j2 = lane + 64;
        float s1 = -1e30f, s2 = -1e30f;
        if (j1 <= i) {
            float acc = 0.f;
            #pragma unroll
            for (int l = 0; l < QK_; ++l) acc += qrs[li][l]*krs[j1][l];
            s1 = acc*scale + sp*(float)(j1 - i);
        }
        if (j2 <= i) {
            float acc = 0.f;
            #pragma unroll
            for (int l = 0; l < QK_; ++l) acc += qrs[li][l]*krs[j2][l];
            s2 = acc*scale + sp*(float)(j2 - i);
        }
        float m = fmaxf(s1, s2);
        #pragma unroll
        for (int off = 32; off; off >>= 1) m = fmaxf(m, __shfl_xor(m, off));
        float p1 = (j1 <= i) ? expf(s1 - m) : 0.f;
        float p2 = (j2 <= i) ? expf(s2 - m) : 0.f;
        float sum = p1 + p2;
        #pragma unroll
        for (int off = 32; off; off >>= 1) sum += __shfl_xor(sum, off);
        float inv = 1.f / sum;
        ushort* prow = P + ((size_t)(b*S_) + i)*128;
        prow[j1] = f2b(p1*inv);
        prow[j2] = f2b(p2*inv);
    }
}

// ------------- attention 2 scores -> normalized P (bf16) -------------
__global__ __launch_bounds__(256)
void attn2_score(const float* __restrict__ q2, const float* __restrict__ k2,
                 ushort* __restrict__ P)
{
    __shared__ float ks[NPTS_][QK_+1];
    int b = blockIdx.x, r0 = blockIdx.y*20;
    int tid = threadIdx.x;
    for (int idx = tid; idx < NPTS_*QK_; idx += 256) {
        int r = idx / QK_, c = idx % QK_;
        ks[r][c] = k2[((size_t)(b*NPTS_ + r))*QK_ + c];
    }
    __syncthreads();
    const float scale = 0.14433756729740643f;
    int w = tid >> 6, lane = tid & 63;
    for (int t = 0; t < 5; ++t) {
        int i = r0 + w + 4*t;
        const float* qr = q2 + ((size_t)(b*S_ + i))*QK_;
        float s[4] = {0.f,0.f,0.f,0.f};
        for (int l = 0; l < QK_; ++l) {
            float ql = qr[l];
            #pragma unroll
            for (int r = 0; r < 4; ++r) s[r] += ql * ks[lane + 64*r][l];
        }
        #pragma unroll
        for (int r = 0; r < 4; ++r) s[r] *= scale;
        float m = fmaxf(fmaxf(s[0],s[1]), fmaxf(s[2],s[3]));
        #pragma unroll
        for (int off = 32; off; off >>= 1) m = fmaxf(m, __shfl_xor(m, off));
        float p[4]; float sum = 0.f;
        #pragma unroll
        for (int r = 0; r < 4; ++r) { p[r] = expf(s[r]-m); sum += p[r]; }
        #pragma unroll
        for (int off = 32; off; off >>= 1) sum += __shfl_xor(sum, off);
        float inv = 1.f / sum;
        ushort* prow = P + ((size_t)(b*S_) + i)*256;
        #pragma unroll
        for (int r = 0; r < 4; ++r) prow[lane + 64*r] = f2b(p[r]*inv);
    }
}

// ------------- P1/P2 = pt_emb @ Wkv halves (fp32) -------------
__global__ __launch_bounds__(256)
void pk_proj(const float* __restrict__ pt_emb, const float* __restrict__ Wkv,
             float* __restrict__ P12)
{
    int e = blockIdx.x*256 + threadIdx.x;
    if (e >= 2*NTOK_*816) return;
    int half = e / (NTOK_*816);
    int rem  = e % (NTOK_*816);
    int t = rem / 816, c = rem % 816;
    const float* x = pt_emb + (size_t)t*192;
    const float* wv = Wkv + (size_t)c*384 + half*192;
    float s = 0.f;
    for (int k = 0; k < 192; ++k) s += x[k]*wv[k];
    P12[e] = s;
}

// ------------- gather pk rows -> k2 (fp32), geglu'd values gv (bf16) -------------
__global__ __launch_bounds__(256)
void pk_gather(const int* __restrict__ pts, const float* __restrict__ P12,
               float* __restrict__ k2, ushort* __restrict__ gv)
{
    int pair = blockIdx.x*4 + (threadIdx.x >> 6);
    int lane = threadIdx.x & 63;
    const float* P1 = P12;
    const float* P2 = P12 + NTOK_*816;
    int t0 = pts[2*pair], t1 = pts[2*pair+1];
    const float* a = P1 + (size_t)t0*816;
    const float* c = P2 + (size_t)t1*816;
    if (lane < QK_) k2[(size_t)pair*QK_ + lane] = a[lane] + c[lane];
    #pragma unroll
    for (int t = 0; t < 6; ++t) {
        int i = lane + 64*t;
        float lin = a[48 + i] + c[48 + i];
        float pre = a[432 + i] + c[432 + i];
        gv[(size_t)pair*D_ + i] = f2b(lin * gelu_f(pre));
    }
}

extern "C" void kernel_launch(void* const* d_in, const int* in_sizes, int n_in,
                              void* d_out, int out_size, void* d_ws, size_t ws_size,
                              hipStream_t stream)
{
    const int*   qtok  = (const int*)d_in[0];
    const int*   pts   = (const int*)d_in[1];
    const float* emb   = (const float*)d_in[2];
    const float* ptemb = (const float*)d_in[3];
    const float* normw = (const float*)d_in[4];
    const float* outw  = (const float*)d_in[5];
    const float* ln1   = (const float*)d_in[6];
    const float* expand= (const float*)d_in[7];
    const float* proj1 = (const float*)d_in[8];
    const float* bm    = (const float*)d_in[9];
    const float* ln2   = (const float*)d_in[10];
    const float* Wq    = (const float*)d_in[11];
    const float* Wkv   = (const float*)d_in[12];
    const float* proj2 = (const float*)d_in[13];
    float* out = (float*)d_out;

    char* base = (char*)d_ws;
    size_t off = 0;
    auto alloc = [&](size_t bytes){ void* p = base + off; off += (bytes + 255) & ~(size_t)255; return p; };
    float*  h     = (float*) alloc((size_t)M_*D_*4);
    ushort* nhi   = (ushort*)alloc((size_t)M_*D_*2);
    ushort* nlo   = (ushort*)alloc((size_t)M_*D_*2);
    float*  qk1   = (float*) alloc((size_t)M_*96*4);     // qr2 aliases
    ushort* geglh = (ushort*)alloc((size_t)M_*E_*2);     // gloc_h aliases
    ushort* gegll = (ushort*)alloc((size_t)M_*E_*2);     // gloc_l aliases
    ushort* atbh  = (ushort*)alloc((size_t)M_*D_*2);
    ushort* atbl  = (ushort*)alloc((size_t)M_*D_*2);
    ushort* Pbuf  = (ushort*)alloc((size_t)M_*256*2);
    ushort* gv    = (ushort*)alloc((size_t)B_*NPTS_*D_*2);
    float*  P12   = (float*) alloc((size_t)2*NTOK_*816*4);
    float*  k2    = (float*) alloc((size_t)B_*NPTS_*QK_*4);
    ushort* wbh   = (ushort*)alloc((size_t)WTOT*2);
    ushort* wbl   = (ushort*)alloc((size_t)WTOT*2);

    float*  qr2   = qk1;
    ushort* gloch = geglh;
    ushort* glocl = gegll;

    const size_t oWE = 0;
    const size_t oP1 = WE_SZ;
    const size_t oWQ = WE_SZ + P1_SZ;
    const size_t oP2 = WE_SZ + P1_SZ + WQ_SZ;

    x_init<<<M_/4, 256, 0, stream>>>(qtok, emb, normw, h, M_);

    for (int blk = 0; blk < NB_; ++blk) {
        wconv<<<(WTOT+255)/256, 256, 0, stream>>>(
            expand + (size_t)blk*WE_SZ, proj1 + (size_t)blk*P1_SZ,
            Wq + (size_t)blk*WQ_SZ, proj2 + (size_t)blk*P2_SZ, wbh, wbl);

        ln_rows<<<M_/4, 256, 0, stream>>>(h, ln1 + blk*D_, nhi, nlo, M_);
        // qk : N=96, K=384
        mm_bt<<<dim3(2, M_/64), 256, 0, stream>>>(nhi, nlo, D_, D_, nhi, nlo, D_,
            wbh + oWE, wbl + oWE, qk1, 96, 96, D_, 0);
        // geglu768
        mm_geglu<<<dim3(12, M_/64), 256, 0, stream>>>(nhi, nlo, D_,
            wbh + oWE + (size_t)96*D_,  wbl + oWE + (size_t)96*D_,
            wbh + oWE + (size_t)864*D_, wbl + oWE + (size_t)864*D_,
            geglh, gegll, E_, E_, D_);
        attn1_score<<<dim3(B_,2), 256, 0, stream>>>(qk1, bm, blk, Pbuf);
        pv_mfma<<<dim3(6,2,B_), 256, 0, stream>>>(Pbuf, 128, (long)S_*128,
            geglh + LOCAL_, E_, (long)S_*E_,
            atbh, atbl, D_, (long)S_*D_, S_, 128, S_);
        // h += [geglu_local | attn] @ W_p1^T
        mm_bt<<<dim3(6, M_/64), 256, 0, stream>>>(geglh, gegll, E_, D_, atbh, atbl, D_,
            wbh + oP1, wbl + oP1, h, D_, D_, E_, 1);

        ln_rows<<<M_/4, 256, 0, stream>>>(h, ln2 + blk*D_, nhi, nlo, M_);
        // qr2 : N=48
        mm_bt<<<dim3(1, M_/64), 256, 0, stream>>>(nhi, nlo, D_, D_, nhi, nlo, D_,
            wbh + oWQ, wbl + oWQ, qr2, QK_, QK_, D_, 0);
        // g_local geglu384
        mm_geglu<<<dim3(6, M_/64), 256, 0, stream>>>(nhi, nlo, D_,
            wbh + oWQ + (size_t)48*D_,  wbl + oWQ + (size_t)48*D_,
            wbh + oWQ + (size_t)432*D_, wbl + oWQ + (size_t)432*D_,
            gloch, glocl, D_, D_, D_);
        // pk path
        pk_proj<<<(2*NTOK_*816 + 255)/256, 256, 0, stream>>>(ptemb,
            Wkv + (size_t)blk*816*D_, P12);
        pk_gather<<<B_*NPTS_/4, 256, 0, stream>>>(pts, P12, k2, gv);
        attn2_score<<<dim3(B_,5), 256, 0, stream>>>(qr2, k2, Pbuf);
        pv_mfma<<<dim3(6,2,B_), 256, 0, stream>>>(Pbuf, 256, (long)S_*256,
            gv, D_, (long)NPTS_*D_,
            atbh, atbl, D_, (long)S_*D_, S_, 256, 256);
        // h += [g_local | attn2] @ W_p2^T
        mm_bt<<<dim3(6, M_/64), 256, 0, stream>>>(gloch, glocl, D_, D_, atbh, atbl, D_,
            wbh + oP2, wbl + oP2, h, D_, D_, E_, 1);
    }

    ln_rows<<<M_/4, 256, 0, stream>>>(h, normw, nhi, nlo, M_);
    wconv1<<<(NTOK_*D_ + 255)/256, 256, 0, stream>>>(outw, NTOK_*D_, wbh, wbl);
    mm_bt<<<dim3(2, M_/64), 256, 0, stream>>>(nhi, nlo, D_, D_, nhi, nlo, D_,
        wbh, wbl, out, NTOK_, NTOK_, D_, 0);
}